// Round 9
// baseline (447.748 us; speedup 1.0000x reference)
//
#include <hip/hip_runtime.h>
#include <hip/hip_bf16.h>
#include <math.h>

#define D_ 3072
#define H_ 2048
#define N_ 16
#define BS_ 512

typedef short s16x8 __attribute__((ext_vector_type(8)));
typedef float f32x4v __attribute__((ext_vector_type(4)));
typedef __hip_bfloat16 bf16;

__device__ __forceinline__ void gload_lds16(const void* g, void* l) {
    __builtin_amdgcn_global_load_lds((const __attribute__((address_space(1))) void*)g,
                                     (__attribute__((address_space(3))) void*)l, 16, 0, 0);
}

__device__ __forceinline__ float bf2f(unsigned short u) {
    unsigned v = (unsigned)u << 16; float f; __builtin_memcpy(&f, &v, 4); return f;
}

// ---------------- split-K NT GEMM: C(f32) += A(M,K)*Bt(N,K)^T over K-chunk ----------------
__global__ __launch_bounds__(256) void mfma_nt_sk(
    const bf16* __restrict__ A, const bf16* __restrict__ Bt,
    float* __restrict__ C, int M, int N, int K, int KC)
{
    __shared__ __align__(16) bf16 As[128 * 32];
    __shared__ __align__(16) bf16 Bs[128 * 32];
    const int tid = threadIdx.x;
    const int w = tid >> 6, l = tid & 63;
    const int wr = w >> 1, wc = w & 1;
    const int m0 = blockIdx.y * 128, n0 = blockIdx.x * 128;
    const int kbeg = blockIdx.z * KC;

    f32x4v acc[4][4];
    #pragma unroll
    for (int a = 0; a < 4; ++a)
        #pragma unroll
        for (int b = 0; b < 4; ++b) acc[a][b] = (f32x4v){0.f, 0.f, 0.f, 0.f};

    const int srow = l >> 2;
    const int scol = (l & 3) * 8;

    for (int k0 = kbeg; k0 < kbeg + KC; k0 += 32) {
        #pragma unroll
        for (int q = 0; q < 2; ++q) {
            int r0 = w * 32 + q * 16;
            gload_lds16(&A[(size_t)(m0 + r0 + srow) * K + k0 + scol], &As[r0 * 32]);
            gload_lds16(&Bt[(size_t)(n0 + r0 + srow) * K + k0 + scol], &Bs[r0 * 32]);
        }
        __syncthreads();
        s16x8 af[4], bfr[4];
        #pragma unroll
        for (int mf = 0; mf < 4; ++mf)
            af[mf] = *(const s16x8*)&As[(wr * 64 + mf * 16 + (l & 15)) * 32 + (l >> 4) * 8];
        #pragma unroll
        for (int nf = 0; nf < 4; ++nf)
            bfr[nf] = *(const s16x8*)&Bs[(wc * 64 + nf * 16 + (l & 15)) * 32 + (l >> 4) * 8];
        #pragma unroll
        for (int mf = 0; mf < 4; ++mf)
            #pragma unroll
            for (int nf = 0; nf < 4; ++nf)
                acc[mf][nf] = __builtin_amdgcn_mfma_f32_16x16x32_bf16(af[mf], bfr[nf], acc[mf][nf], 0, 0, 0);
        __syncthreads();
    }

    #pragma unroll
    for (int mf = 0; mf < 4; ++mf)
        #pragma unroll
        for (int nf = 0; nf < 4; ++nf) {
            int n = n0 + wc * 64 + nf * 16 + (l & 15);
            #pragma unroll
            for (int r = 0; r < 4; ++r) {
                int m = m0 + wr * 64 + mf * 16 + (l >> 4) * 4 + r;
                atomicAdd(&C[(size_t)m * N + n], acc[mf][nf][r]);
            }
        }
}

// ---------------- epilogues ----------------
__global__ __launch_bounds__(256) void ep_ebf(const float* __restrict__ C,
    const float* __restrict__ bias, const float* __restrict__ X,
    bf16* __restrict__ Eout, int MN, int N)
{
    int base = (blockIdx.x * 256 + threadIdx.x) * 8;
    if (base < MN) {
        float4 c0 = *(const float4*)&C[base];
        float4 c1 = *(const float4*)&C[base + 4];
        float4 x0 = *(const float4*)&X[base];
        float4 x1 = *(const float4*)&X[base + 4];
        int n = base % N;
        float4 b0 = *(const float4*)&bias[n];
        float4 b1 = *(const float4*)&bias[n + 4];
        union { s16x8 v; bf16 e[8]; } u;
        u.e[0] = __float2bfloat16(x0.x - (c0.x + b0.x));
        u.e[1] = __float2bfloat16(x0.y - (c0.y + b0.y));
        u.e[2] = __float2bfloat16(x0.z - (c0.z + b0.z));
        u.e[3] = __float2bfloat16(x0.w - (c0.w + b0.w));
        u.e[4] = __float2bfloat16(x1.x - (c1.x + b1.x));
        u.e[5] = __float2bfloat16(x1.y - (c1.y + b1.y));
        u.e[6] = __float2bfloat16(x1.z - (c1.z + b1.z));
        u.e[7] = __float2bfloat16(x1.w - (c1.w + b1.w));
        *(s16x8*)&Eout[base] = u.v;
    }
}

__global__ __launch_bounds__(256) void ep_recon(const float* __restrict__ C,
    const float* __restrict__ bias, const float* __restrict__ X, float* __restrict__ rls)
{
    int m = blockIdx.x;
    float s = 0.f;
    for (int n = threadIdx.x * 4; n < D_; n += 1024) {
        float4 c = *(const float4*)&C[(size_t)m * D_ + n];
        float4 bb = *(const float4*)&bias[n];
        float4 xx = *(const float4*)&X[(size_t)m * D_ + n];
        float v0 = c.x + bb.x - xx.x, v1 = c.y + bb.y - xx.y;
        float v2 = c.z + bb.z - xx.z, v3 = c.w + bb.w - xx.w;
        s += v0 * v0 + v1 * v1 + v2 * v2 + v3 * v3;
    }
    __shared__ float red[4];
    int wid = threadIdx.x >> 6, lane = threadIdx.x & 63;
    #pragma unroll
    for (int off = 32; off; off >>= 1) s += __shfl_xor(s, off);
    if (lane == 0) red[wid] = s;
    __syncthreads();
    if (threadIdx.x == 0) rls[m] = red[0] + red[1] + red[2] + red[3];
}

// ---------------- fused J-GEMM + J^T J: 256x128 tile, BK=32, 2-barrier structure ----------------
// Wave w computes rows [w*64, w*64+64) x 128 cols: 12 ds_read / 32 MFMA per K-step
// (vs 8/16 at 128^2) -> barrier overhead per MFMA halves. Epilogue: 16 batch strips,
// 4 per wave, validated self-product pattern (round 5).
__global__ __launch_bounds__(256) void jtj_fused(
    const bf16* __restrict__ Vt, const bf16* __restrict__ W2t,
    float* __restrict__ S, int Mb, int b0)
{
    __shared__ union {
        struct { __align__(16) bf16 As[256 * 32]; __align__(16) bf16 Bs[128 * 32]; } s;  // 24 KB
        __align__(16) bf16 J[256 * 136];                                                  // 69.6 KB
    } u;
    const int tid = threadIdx.x;
    const int w = tid >> 6, l = tid & 63;

    int mb, nbk;
    if ((Mb & 7) == 0) {
        int lin = blockIdx.y * 24 + blockIdx.x;
        int xcd = lin & 7, idx = lin >> 3;
        int mchunk = Mb >> 3;
        mb = xcd * mchunk + idx / 24;
        nbk = idx % 24;
    } else { mb = blockIdx.y; nbk = blockIdx.x; }
    const int m0 = mb * 256, n0 = nbk * 128;

    f32x4v acc[4][8];
    #pragma unroll
    for (int a = 0; a < 4; ++a)
        #pragma unroll
        for (int b = 0; b < 8; ++b) acc[a][b] = (f32x4v){0.f, 0.f, 0.f, 0.f};

    const int srow = l >> 2;
    const int scol = (l & 3) * 8;

    for (int k0 = 0; k0 < H_; k0 += 32) {
        #pragma unroll
        for (int q = 0; q < 4; ++q) {
            int r0 = w * 64 + q * 16;
            gload_lds16(&Vt[(size_t)(m0 + r0 + srow) * H_ + k0 + scol], &u.s.As[r0 * 32]);
        }
        #pragma unroll
        for (int q = 0; q < 2; ++q) {
            int r0 = w * 32 + q * 16;
            gload_lds16(&W2t[(size_t)(n0 + r0 + srow) * H_ + k0 + scol], &u.s.Bs[r0 * 32]);
        }
        __syncthreads();
        s16x8 af[4], bfr[8];
        #pragma unroll
        for (int mf = 0; mf < 4; ++mf)
            af[mf] = *(const s16x8*)&u.s.As[(w * 64 + mf * 16 + (l & 15)) * 32 + (l >> 4) * 8];
        #pragma unroll
        for (int nf = 0; nf < 8; ++nf)
            bfr[nf] = *(const s16x8*)&u.s.Bs[(nf * 16 + (l & 15)) * 32 + (l >> 4) * 8];
        #pragma unroll
        for (int mf = 0; mf < 4; ++mf)
            #pragma unroll
            for (int nf = 0; nf < 8; ++nf)
                acc[mf][nf] = __builtin_amdgcn_mfma_f32_16x16x32_bf16(af[mf], bfr[nf], acc[mf][nf], 0, 0, 0);
        __syncthreads();
    }

    // ---- epilogue: J (bf16) -> LDS, per-strip self-product ----
    __syncthreads();
    #pragma unroll
    for (int mf = 0; mf < 4; ++mf) {
        int rbase = w * 64 + mf * 16 + (l >> 4) * 4;
        #pragma unroll
        for (int nf = 0; nf < 8; ++nf) {
            int col = nf * 16 + (l & 15);
            #pragma unroll
            for (int r = 0; r < 4; ++r)
                u.J[(size_t)(rbase + r) * 136 + col] = __float2bfloat16(acc[mf][nf][r]);
        }
    }
    __syncthreads();

    #pragma unroll
    for (int s4 = 0; s4 < 4; ++s4) {
        int bl = w * 4 + s4;                 // batch strip 0..15
        f32x4v sp = (f32x4v){0.f, 0.f, 0.f, 0.f};
        #pragma unroll
        for (int kq = 0; kq < 4; ++kq) {
            s16x8 fr = *(const s16x8*)&u.J[(size_t)(bl * 16 + (l & 15)) * 136 + kq * 32 + (l >> 4) * 8];
            sp = __builtin_amdgcn_mfma_f32_16x16x32_bf16(fr, fr, sp, 0, 0, 0);
        }
        int bglob = b0 + mb * 16 + bl;
        #pragma unroll
        for (int r = 0; r < 4; ++r)
            atomicAdd(&S[(size_t)bglob * 256 + ((l >> 4) * 4 + r) * 16 + (l & 15)], sp[r]);
    }
}

// ---------------- hessian via MFMA ----------------
__global__ __launch_bounds__(256) void hess_mfma(const float* __restrict__ t,
    const float* __restrict__ g, const bf16* __restrict__ W1b, float* __restrict__ S)
{
    const int w = threadIdx.x >> 6, l = threadIdx.x & 63;
    const int b = blockIdx.x * 4 + w;
    const int row = l & 15, kq = (l >> 4) * 8;

    f32x4v sp = (f32x4v){0.f, 0.f, 0.f, 0.f};
    for (int k0 = 0; k0 < H_; k0 += 32) {
        int kk = k0 + kq;
        s16x8 wf = *(const s16x8*)&W1b[(size_t)row * H_ + kk];
        float4 t0 = *(const float4*)&t[(size_t)b * H_ + kk];
        float4 t1 = *(const float4*)&t[(size_t)b * H_ + kk + 4];
        float4 g0 = *(const float4*)&g[(size_t)b * H_ + kk];
        float4 g1 = *(const float4*)&g[(size_t)b * H_ + kk + 4];
        float wv[8];
        wv[0] = 2.f * g0.x * t0.x * (1.f - t0.x * t0.x);
        wv[1] = 2.f * g0.y * t0.y * (1.f - t0.y * t0.y);
        wv[2] = 2.f * g0.z * t0.z * (1.f - t0.z * t0.z);
        wv[3] = 2.f * g0.w * t0.w * (1.f - t0.w * t0.w);
        wv[4] = 2.f * g1.x * t1.x * (1.f - t1.x * t1.x);
        wv[5] = 2.f * g1.y * t1.y * (1.f - t1.y * t1.y);
        wv[6] = 2.f * g1.z * t1.z * (1.f - t1.z * t1.z);
        wv[7] = 2.f * g1.w * t1.w * (1.f - t1.w * t1.w);
        union { s16x8 v; bf16 e[8]; } af;
        #pragma unroll
        for (int e = 0; e < 8; ++e)
            af.e[e] = __float2bfloat16(wv[e] * bf2f((unsigned short)wf[e]));
        sp = __builtin_amdgcn_mfma_f32_16x16x32_bf16(af.v, wf, sp, 0, 0, 0);
    }
    #pragma unroll
    for (int r = 0; r < 4; ++r)
        S[(size_t)b * 256 + ((l >> 4) * 4 + r) * 16 + (l & 15)] += sp[r];
}

// ---------------- fused prep: all casts in one launch ----------------
__global__ __launch_bounds__(256) void prep_all(
    const float* __restrict__ x, const float* __restrict__ enc_W1,
    const float* __restrict__ dec_W2, const float* __restrict__ dec_W1,
    bf16* __restrict__ x_bf, bf16* __restrict__ eW1t,
    bf16* __restrict__ W2t, bf16* __restrict__ W2b, bf16* __restrict__ W1b)
{
    __shared__ float tile[64][65];
    const int blk = blockIdx.x;
    const int tid = threadIdx.x;
    if (blk < 768) {
        int i = blk * 256 + tid;
        const float4* p = (const float4*)x + (size_t)i * 2;
        float4 a = p[0], b = p[1];
        union { s16x8 v; bf16 e[8]; } u;
        u.e[0] = __float2bfloat16(a.x); u.e[1] = __float2bfloat16(a.y);
        u.e[2] = __float2bfloat16(a.z); u.e[3] = __float2bfloat16(a.w);
        u.e[4] = __float2bfloat16(b.x); u.e[5] = __float2bfloat16(b.y);
        u.e[6] = __float2bfloat16(b.z); u.e[7] = __float2bfloat16(b.w);
        *(s16x8*)&x_bf[(size_t)i * 8] = u.v;
    } else if (blk < 768 + 1536) {
        int bid = blk - 768;
        int r0 = (bid % 48) * 64, c0 = (bid / 48) * 64;
        int tx = tid & 63, ty = tid >> 6;
        #pragma unroll
        for (int k = 0; k < 16; ++k) {
            int rr = ty * 16 + k;
            tile[rr][tx] = enc_W1[(size_t)(r0 + rr) * H_ + c0 + tx];
        }
        __syncthreads();
        #pragma unroll
        for (int k = 0; k < 16; ++k) {
            int cc = ty * 16 + k;
            eW1t[(size_t)(c0 + cc) * D_ + r0 + tx] = __float2bfloat16(tile[tx][cc]);
        }
    } else if (blk < 768 + 3072) {
        int bid = blk - 768 - 1536;
        int r0 = (bid % 32) * 64, c0 = (bid / 32) * 64;
        int tx = tid & 63, ty = tid >> 6;
        #pragma unroll
        for (int k = 0; k < 16; ++k) {
            int rr = ty * 16 + k;
            float v = dec_W2[(size_t)(r0 + rr) * D_ + c0 + tx];
            tile[rr][tx] = v;
            W2b[(size_t)(r0 + rr) * D_ + c0 + tx] = __float2bfloat16(v);
        }
        __syncthreads();
        #pragma unroll
        for (int k = 0; k < 16; ++k) {
            int cc = ty * 16 + k;
            W2t[(size_t)(c0 + cc) * H_ + r0 + tx] = __float2bfloat16(tile[tx][cc]);
        }
    } else {
        int i = (blk - 768 - 3072) * 256 + tid;
        if (i < N_ * H_ / 8) {
            const float4* p = (const float4*)dec_W1 + (size_t)i * 2;
            float4 a = p[0], b = p[1];
            union { s16x8 v; bf16 e[8]; } u;
            u.e[0] = __float2bfloat16(a.x); u.e[1] = __float2bfloat16(a.y);
            u.e[2] = __float2bfloat16(a.z); u.e[3] = __float2bfloat16(a.w);
            u.e[4] = __float2bfloat16(b.x); u.e[5] = __float2bfloat16(b.y);
            u.e[6] = __float2bfloat16(b.z); u.e[7] = __float2bfloat16(b.w);
            *(s16x8*)&W1b[(size_t)i * 8] = u.v;
        }
    }
}

// ---------------- zsig + build_t fused ----------------
__global__ __launch_bounds__(256) void zsig_t_kernel(const float* __restrict__ Ch,
    const float* __restrict__ enc_b1, const float* __restrict__ Wmu, const float* __restrict__ bmu,
    const float* __restrict__ Wls, const float* __restrict__ bls,
    const float* __restrict__ dW1, const float* __restrict__ db1,
    float* __restrict__ z_star, float* __restrict__ lsig, float* __restrict__ sigma,
    float* __restrict__ t, bf16* __restrict__ tb)
{
    const int b = blockIdx.x, tid = threadIdx.x;
    float acc[17];
    #pragma unroll
    for (int i = 0; i < 17; ++i) acc[i] = 0.f;
    for (int hh = tid; hh < H_; hh += 256) {
        float hv = tanhf(Ch[(size_t)b * H_ + hh] + enc_b1[hh]);
        const float* wr = &Wmu[(size_t)hh * 16];
        #pragma unroll
        for (int i = 0; i < 16; ++i) acc[i] += hv * wr[i];
        acc[16] += hv * Wls[hh];
    }
    __shared__ float red[17][4];
    __shared__ float zs[16];
    const int wid = tid >> 6, lane = tid & 63;
    #pragma unroll
    for (int i = 0; i < 17; ++i) {
        float v = acc[i];
        #pragma unroll
        for (int off = 32; off; off >>= 1) v += __shfl_xor(v, off);
        if (lane == 0) red[i][wid] = v;
    }
    __syncthreads();
    if (tid < 17) {
        float v = red[tid][0] + red[tid][1] + red[tid][2] + red[tid][3];
        if (tid < 16) { float z = v + bmu[tid]; zs[tid] = z; z_star[(size_t)b * 16 + tid] = z; }
        else { float ls = v + bls[0]; lsig[b] = ls; sigma[b] = expf(ls); }
    }
    __syncthreads();
    for (int hh = tid; hh < H_; hh += 256) {
        float a = db1[hh];
        #pragma unroll
        for (int i = 0; i < 16; ++i) a += zs[i] * dW1[(size_t)i * H_ + hh];
        float tv = tanhf(a);
        t[(size_t)b * H_ + hh] = tv;
        tb[(size_t)b * H_ + hh] = __float2bfloat16(tv);
    }
}

// t = tanh(z @ W1 + b1), bf16 out only
__global__ __launch_bounds__(256) void build_t(const float* __restrict__ z,
    const float* __restrict__ W1, const float* __restrict__ b1, bf16* __restrict__ tb)
{
    __shared__ float zs[16];
    int b = blockIdx.x, tid = threadIdx.x;
    if (tid < 16) zs[tid] = z[(size_t)b * 16 + tid];
    __syncthreads();
    for (int hh = tid; hh < H_; hh += 256) {
        float a = b1[hh];
        #pragma unroll
        for (int i = 0; i < 16; ++i) a += zs[i] * W1[(size_t)i * H_ + hh];
        tb[(size_t)b * H_ + hh] = __float2bfloat16(tanhf(a));
    }
}

// Vt[(b_local*16+i), h] = (1-t^2) * W1[i,h]  (bf16)
__global__ __launch_bounds__(256) void build_vt(const float* __restrict__ t,
    const float* __restrict__ W1, bf16* __restrict__ Vt, int b0)
{
    int bl = blockIdx.x, b = b0 + bl, tid = threadIdx.x;
    __shared__ float u[H_];
    for (int hh = tid; hh < H_; hh += 256) {
        float tv = t[(size_t)b * H_ + hh];
        u[hh] = 1.f - tv * tv;
    }
    __syncthreads();
    size_t base = (size_t)bl * 16 * H_;
    int hh = tid * 8;
    for (int i = 0; i < 16; ++i) {
        union { s16x8 v; bf16 e[8]; } pk;
        #pragma unroll
        for (int k = 0; k < 8; ++k)
            pk.e[k] = __float2bfloat16(u[hh + k] * W1[(size_t)i * H_ + hh + k]);
        *(s16x8*)&Vt[base + (size_t)i * H_ + hh] = pk.v;
    }
}

// ---------------- per-batch 16x16: barrier-free register solve ----------------
__global__ __launch_bounds__(64) void solve_kernel(const float* __restrict__ S,
    const float* __restrict__ sigma, const float* __restrict__ z_star,
    const float* __restrict__ eps, float* __restrict__ z_sample, float* __restrict__ d_out)
{
    const int lane = threadIdx.x;
    const int q = lane >> 4;
    const int j = lane & 15;
    const int b = blockIdx.x * 4 + q;

    const float sg = sigma[b];
    const float inv_s2 = 1.0f / (sg * sg);

    float a0[16], a[16];
    #pragma unroll
    for (int r = 0; r < 16; ++r) {
        a0[r] = S[(size_t)b * 256 + r * 16 + j] * inv_s2 + ((r == j) ? 1.0f : 0.0f);
        a[r] = a0[r];
    }

    #pragma unroll
    for (int k = 0; k < 14; ++k) {
        float x[16];
        #pragma unroll
        for (int r = 0; r < 16; ++r) x[r] = __shfl(a[k], r, 16);
        float sig2 = 0.f;
        #pragma unroll
        for (int r = 0; r < 16; ++r) if (r > k + 1) sig2 += x[r] * x[r];
        float x0 = x[k + 1];
        float normx = sqrtf(sig2 + x0 * x0);
        float alpha = (x0 >= 0.f) ? -normx : normx;
        float v[16];
        #pragma unroll
        for (int r = 0; r < 16; ++r)
            v[r] = (r <= k) ? 0.f : ((r == k + 1) ? x0 - alpha : x[r]);
        float vtv = 0.f;
        #pragma unroll
        for (int r = 0; r < 16; ++r) vtv += v[r] * v[r];
        float beta = (vtv > 1e-28f) ? 2.0f / vtv : 0.f;
        float sj = 0.f;
        #pragma unroll
        for (int r = 0; r < 16; ++r) sj += a[r] * v[r];
        float av[16];
        #pragma unroll
        for (int r = 0; r < 16; ++r) av[r] = __shfl(sj, r, 16);
        float vtav = 0.f;
        #pragma unroll
        for (int r = 0; r < 16; ++r) vtav += v[r] * av[r];
        float c = 0.5f * beta * vtav;
        float wv[16];
        #pragma unroll
        for (int r = 0; r < 16; ++r) wv[r] = beta * (av[r] - c * v[r]);
        float vj = (j <= k) ? 0.f : ((j == k + 1) ? a[k] - alpha : a[k]);
        float wj = beta * (sj - c * vj);
        #pragma unroll
        for (int r = 0; r < 16; ++r) a[r] -= v[r] * wj + wv[r] * vj;
    }

    float dg[16], eo[15];
    #pragma unroll
    for (int r = 0; r < 16; ++r) dg[r] = __shfl(a[r], r, 16);
    #pragma unroll
    for (int r = 0; r < 15; ++r) eo[r] = __shfl(a[r + 1], r, 16);

    float lo = 1e30f, hi = 1e30f;
    #pragma unroll
    for (int r = 0; r < 16; ++r) {
        float rad = ((r > 0) ? fabsf(eo[r - 1]) : 0.f) + ((r < 15) ? fabsf(eo[r]) : 0.f);
        lo = fminf(lo, dg[r] - rad);
        hi = fminf(hi, dg[r]);
    }
    lo -= 1e-4f; hi += 1e-4f;

    #pragma unroll
    for (int pass = 0; pass < 5; ++pass) {
        float step = (hi - lo) * (1.0f / 17.0f);
        float s = lo + step * (float)(j + 1);
        float qq = dg[0] - s;
        int cnt = (qq < 0.f) ? 1 : 0;
        #pragma unroll
        for (int i = 1; i < 16; ++i) {
            float denom = (fabsf(qq) < 1e-30f) ? -1e-30f : qq;
            qq = dg[i] - s - eo[i - 1] * eo[i - 1] / denom;
            cnt += (qq < 0.f) ? 1 : 0;
        }
        unsigned long long bal = __ballot(cnt >= 1);
        unsigned grp = (unsigned)((bal >> (q * 16)) & 0xffffull);
        int f = grp ? (__ffs(grp) - 1) : 16;
        float nlo = lo + step * (float)f;
        float nhi = (f < 16) ? (lo + step * (float)(f + 1)) : hi;
        lo = nlo; hi = nhi;
    }
    const float lam_min = 0.5f * (lo + hi);
    const float delta = 10.0f - lam_min;

    float bm[16];
    #pragma unroll
    for (int r = 0; r < 16; ++r) bm[r] = a0[r] + ((r == j) ? delta : 0.f);

    float ldsum = 0.f;
    #pragma unroll
    for (int kk = 0; kk < 16; ++kk) {
        float ck[16];
        #pragma unroll
        for (int r = 0; r < 16; ++r) ck[r] = __shfl(bm[kk], r, 16);
        float dkk = sqrtf(fmaxf(ck[kk], 1e-30f));
        float inv = 1.0f / dkk;
        ldsum += logf(dkk);
        float lfull[16];
        #pragma unroll
        for (int r = 0; r < 16; ++r) lfull[r] = ck[r] * inv;
        float lj = bm[kk] * inv;
        if (j == kk) {
            #pragma unroll
            for (int r = 0; r < 16; ++r) bm[r] = (r >= kk) ? lfull[r] : 0.f;
        } else if (j > kk) {
            #pragma unroll
            for (int r = 0; r < 16; ++r)
                if (r > kk) bm[r] -= lfull[r] * lj;
        }
    }

    float w[16];
    #pragma unroll
    for (int r = 0; r < 16; ++r) w[r] = 0.f;
    #pragma unroll
    for (int i = 0; i < 16; ++i) {
        float row[16];
        #pragma unroll
        for (int kx = 0; kx < 16; ++kx) row[kx] = __shfl(bm[i], kx, 16);
        float sacc = 0.f;
        #pragma unroll
        for (int kx = 0; kx < 16; ++kx) if (kx < i) sacc += row[kx] * w[kx];
        float invd = 1.0f / row[i];
        float val = (i == j) ? invd : (-sacc * invd);
        w[i] = (i >= j) ? val : 0.f;
    }

    float tsum = 0.f;
    #pragma unroll
    for (int r = 0; r < 16; ++r) tsum += w[r] * w[r];
    float zv = z_star[(size_t)b * 16 + j];
    float ep = eps[(size_t)b * 16 + j];
    float epsv[16];
    #pragma unroll
    for (int r = 0; r < 16; ++r) epsv[r] = __shfl(ep, r, 16);
    float zoff = 0.f;
    #pragma unroll
    for (int r = 0; r < 16; ++r) zoff += w[r] * epsv[r];
    z_sample[(size_t)b * 16 + j] = zv + zoff;

    float zsq = zv * zv;
    #pragma unroll
    for (int off = 1; off < 16; off <<= 1) {
        tsum += __shfl_xor(tsum, off);
        zsq  += __shfl_xor(zsq, off);
    }
    if (j == 0) {
        d_out[2 * 512 + b] = 0.5f * zsq + 0.5f * tsum;
        d_out[3 * 512 + b] = ldsum;
        d_out[4 * 512 + b] = sg;
    }
}

__global__ void finalize_kernel(const float* __restrict__ rlsum, const float* __restrict__ sigma,
    const float* __restrict__ lsig, float* __restrict__ d_out)
{
    int b = blockIdx.x * 256 + threadIdx.x;
    if (b < BS_) {
        float sg = sigma[b];
        float rl = rlsum[b] / (2.0f * sg * sg);
        float le = d_out[2 * 512 + b];
        float ld = d_out[3 * 512 + b];
        d_out[b] = (rl + le + ld) / 3072.0f + lsig[b];
        d_out[512 + b] = rl;
    }
}

extern "C" void kernel_launch(void* const* d_in, const int* in_sizes, int n_in,
                              void* d_out, int out_size, void* d_ws, size_t ws_size,
                              hipStream_t stream)
{
    const float* x       = (const float*)d_in[0];
    const float* eps     = (const float*)d_in[1];
    const float* enc_W1  = (const float*)d_in[2];
    const float* enc_b1  = (const float*)d_in[3];
    const float* enc_Wmu = (const float*)d_in[4];
    const float* enc_bmu = (const float*)d_in[5];
    const float* enc_Wls = (const float*)d_in[6];
    const float* enc_bls = (const float*)d_in[7];
    const float* dec_W1  = (const float*)d_in[8];
    const float* dec_b1  = (const float*)d_in[9];
    const float* dec_W2  = (const float*)d_in[10];
    const float* dec_b2  = (const float*)d_in[11];
    float* out = (float*)d_out;

    char* wsb = (char*)d_ws;
    size_t off = 0;
    auto alloc = [&](size_t bytes) -> void* {
        off = (off + 255) & ~(size_t)255;
        void* p = wsb + off;
        off += bytes;
        return p;
    };

    float* Ch   = (float*)alloc((size_t)BS_ * H_ * 4);
    float* Cd   = (float*)alloc((size_t)BS_ * D_ * 4);
    float* g    = (float*)alloc((size_t)BS_ * H_ * 4);
    float* S    = (float*)alloc((size_t)BS_ * 256 * 4);
    size_t zero_span = (size_t)((char*)(S + BS_ * 256) - (char*)Ch);

    float* t    = (float*)alloc((size_t)BS_ * H_ * 4);
    float* z_st = (float*)alloc((size_t)BS_ * 16 * 4);
    float* lsig = (float*)alloc(BS_ * 4);
    float* sigm = (float*)alloc(BS_ * 4);
    float* z_sm = (float*)alloc((size_t)BS_ * 16 * 4);
    float* rls  = (float*)alloc(BS_ * 4);
    bf16* x_bf  = (bf16*)alloc((size_t)BS_ * D_ * 2);
    bf16* eW1t  = (bf16*)alloc((size_t)H_ * D_ * 2);
    bf16* W2b   = (bf16*)alloc((size_t)H_ * D_ * 2);
    bf16* W2t   = (bf16*)alloc((size_t)D_ * H_ * 2);
    bf16* W1b   = (bf16*)alloc((size_t)N_ * H_ * 2);
    bf16* t_bf  = (bf16*)alloc((size_t)BS_ * H_ * 2);
    bf16* e_bf  = (bf16*)alloc((size_t)BS_ * D_ * 2);
    bf16* t2b   = (bf16*)alloc((size_t)BS_ * H_ * 2);

    int nb = 0;
    size_t base_off = off;
    const int cand[3] = {512, 128, 32};
    bf16* Vt = nullptr;
    for (int ci = 0; ci < 3; ++ci) {
        off = base_off;
        int n = cand[ci];
        bf16* vt = (bf16*)alloc((size_t)n * 16 * H_ * 2);
        if (off <= ws_size) { nb = n; Vt = vt; break; }
    }
    if (nb == 0) return;

    prep_all<<<dim3(768 + 3072 + 16), 256, 0, stream>>>(
        x, enc_W1, dec_W2, dec_W1, x_bf, eW1t, W2t, W2b, W1b);
    hipMemsetAsync(Ch, 0, zero_span, stream);

    mfma_nt_sk<<<dim3(H_ / 128, BS_ / 128, 4), 256, 0, stream>>>(
        x_bf, eW1t, Ch, BS_, H_, D_, D_ / 4);
    zsig_t_kernel<<<dim3(BS_), 256, 0, stream>>>(Ch, enc_b1, enc_Wmu, enc_bmu, enc_Wls, enc_bls,
        dec_W1, dec_b1, z_st, lsig, sigm, t, t_bf);
    mfma_nt_sk<<<dim3(D_ / 128, BS_ / 128, 4), 256, 0, stream>>>(
        t_bf, W2t, Cd, BS_, D_, H_, H_ / 4);
    ep_ebf<<<dim3(BS_ * D_ / 8 / 256), 256, 0, stream>>>(Cd, dec_b2, x, e_bf, BS_ * D_, D_);
    mfma_nt_sk<<<dim3(H_ / 128, BS_ / 128, 4), 256, 0, stream>>>(
        e_bf, W2b, g, BS_, H_, D_, D_ / 4);

    // S = J^T J (256x128 tile, fused epilogue)
    for (int b0 = 0; b0 < BS_; b0 += nb) {
        build_vt<<<dim3(nb), 256, 0, stream>>>(t, dec_W1, Vt, b0);
        int Mb = nb * 16 / 256;
        jtj_fused<<<dim3(D_ / 128, Mb), 256, 0, stream>>>(Vt, W2t, S, Mb, b0);
    }
    hess_mfma<<<dim3(BS_ / 4), 256, 0, stream>>>(t, g, W1b, S);

    solve_kernel<<<dim3(BS_ / 4), 64, 0, stream>>>(S, sigm, z_st, eps, z_sm, out);
    build_t<<<dim3(BS_), 256, 0, stream>>>(z_sm, dec_W1, dec_b1, t2b);
    hipMemsetAsync(Cd, 0, (size_t)BS_ * D_ * 4, stream);
    mfma_nt_sk<<<dim3(D_ / 128, BS_ / 128, 4), 256, 0, stream>>>(
        t2b, W2t, Cd, BS_, D_, H_, H_ / 4);
    ep_recon<<<dim3(BS_), 256, 0, stream>>>(Cd, dec_b2, x, rls);
    finalize_kernel<<<dim3(2), 256, 0, stream>>>(rls, sigm, lsig, out);
}

// Round 10
// 359.526 us; speedup vs baseline: 1.2454x; 1.2454x over previous
//
#include <hip/hip_runtime.h>
#include <hip/hip_bf16.h>
#include <math.h>

#define D_ 3072
#define H_ 2048
#define N_ 16
#define BS_ 512

typedef short s16x8 __attribute__((ext_vector_type(8)));
typedef float f32x4v __attribute__((ext_vector_type(4)));
typedef __hip_bfloat16 bf16;

__device__ __forceinline__ void gload_lds16(const void* g, void* l) {
    __builtin_amdgcn_global_load_lds((const __attribute__((address_space(1))) void*)g,
                                     (__attribute__((address_space(3))) void*)l, 16, 0, 0);
}

__device__ __forceinline__ float bf2f(unsigned short u) {
    unsigned v = (unsigned)u << 16; float f; __builtin_memcpy(&f, &v, 4); return f;
}

// ---------------- split-K NT GEMM: C(f32) += A(M,K)*Bt(N,K)^T over K-chunk ----------------
__global__ __launch_bounds__(256) void mfma_nt_sk(
    const bf16* __restrict__ A, const bf16* __restrict__ Bt,
    float* __restrict__ C, int M, int N, int K, int KC)
{
    __shared__ __align__(16) bf16 As[128 * 32];
    __shared__ __align__(16) bf16 Bs[128 * 32];
    const int tid = threadIdx.x;
    const int w = tid >> 6, l = tid & 63;
    const int wr = w >> 1, wc = w & 1;
    const int m0 = blockIdx.y * 128, n0 = blockIdx.x * 128;
    const int kbeg = blockIdx.z * KC;

    f32x4v acc[4][4];
    #pragma unroll
    for (int a = 0; a < 4; ++a)
        #pragma unroll
        for (int b = 0; b < 4; ++b) acc[a][b] = (f32x4v){0.f, 0.f, 0.f, 0.f};

    const int srow = l >> 2;
    const int scol = (l & 3) * 8;

    for (int k0 = kbeg; k0 < kbeg + KC; k0 += 32) {
        #pragma unroll
        for (int q = 0; q < 2; ++q) {
            int r0 = w * 32 + q * 16;
            gload_lds16(&A[(size_t)(m0 + r0 + srow) * K + k0 + scol], &As[r0 * 32]);
            gload_lds16(&Bt[(size_t)(n0 + r0 + srow) * K + k0 + scol], &Bs[r0 * 32]);
        }
        __syncthreads();
        s16x8 af[4], bfr[4];
        #pragma unroll
        for (int mf = 0; mf < 4; ++mf)
            af[mf] = *(const s16x8*)&As[(wr * 64 + mf * 16 + (l & 15)) * 32 + (l >> 4) * 8];
        #pragma unroll
        for (int nf = 0; nf < 4; ++nf)
            bfr[nf] = *(const s16x8*)&Bs[(wc * 64 + nf * 16 + (l & 15)) * 32 + (l >> 4) * 8];
        #pragma unroll
        for (int mf = 0; mf < 4; ++mf)
            #pragma unroll
            for (int nf = 0; nf < 4; ++nf)
                acc[mf][nf] = __builtin_amdgcn_mfma_f32_16x16x32_bf16(af[mf], bfr[nf], acc[mf][nf], 0, 0, 0);
        __syncthreads();
    }

    #pragma unroll
    for (int mf = 0; mf < 4; ++mf)
        #pragma unroll
        for (int nf = 0; nf < 4; ++nf) {
            int n = n0 + wc * 64 + nf * 16 + (l & 15);
            #pragma unroll
            for (int r = 0; r < 4; ++r) {
                int m = m0 + wr * 64 + mf * 16 + (l >> 4) * 4 + r;
                atomicAdd(&C[(size_t)m * N + n], acc[mf][nf][r]);
            }
        }
}

// ---------------- epilogues ----------------
__global__ __launch_bounds__(256) void ep_ebf(const float* __restrict__ C,
    const float* __restrict__ bias, const float* __restrict__ X,
    bf16* __restrict__ Eout, int MN, int N)
{
    int base = (blockIdx.x * 256 + threadIdx.x) * 8;
    if (base < MN) {
        float4 c0 = *(const float4*)&C[base];
        float4 c1 = *(const float4*)&C[base + 4];
        float4 x0 = *(const float4*)&X[base];
        float4 x1 = *(const float4*)&X[base + 4];
        int n = base % N;
        float4 b0 = *(const float4*)&bias[n];
        float4 b1 = *(const float4*)&bias[n + 4];
        union { s16x8 v; bf16 e[8]; } u;
        u.e[0] = __float2bfloat16(x0.x - (c0.x + b0.x));
        u.e[1] = __float2bfloat16(x0.y - (c0.y + b0.y));
        u.e[2] = __float2bfloat16(x0.z - (c0.z + b0.z));
        u.e[3] = __float2bfloat16(x0.w - (c0.w + b0.w));
        u.e[4] = __float2bfloat16(x1.x - (c1.x + b1.x));
        u.e[5] = __float2bfloat16(x1.y - (c1.y + b1.y));
        u.e[6] = __float2bfloat16(x1.z - (c1.z + b1.z));
        u.e[7] = __float2bfloat16(x1.w - (c1.w + b1.w));
        *(s16x8*)&Eout[base] = u.v;
    }
}

__global__ __launch_bounds__(256) void ep_recon(const float* __restrict__ C,
    const float* __restrict__ bias, const float* __restrict__ X, float* __restrict__ rls)
{
    int m = blockIdx.x;
    float s = 0.f;
    for (int n = threadIdx.x * 4; n < D_; n += 1024) {
        float4 c = *(const float4*)&C[(size_t)m * D_ + n];
        float4 bb = *(const float4*)&bias[n];
        float4 xx = *(const float4*)&X[(size_t)m * D_ + n];
        float v0 = c.x + bb.x - xx.x, v1 = c.y + bb.y - xx.y;
        float v2 = c.z + bb.z - xx.z, v3 = c.w + bb.w - xx.w;
        s += v0 * v0 + v1 * v1 + v2 * v2 + v3 * v3;
    }
    __shared__ float red[4];
    int wid = threadIdx.x >> 6, lane = threadIdx.x & 63;
    #pragma unroll
    for (int off = 32; off; off >>= 1) s += __shfl_xor(s, off);
    if (lane == 0) red[wid] = s;
    __syncthreads();
    if (threadIdx.x == 0) rls[m] = red[0] + red[1] + red[2] + red[3];
}

// ---------------- fused J-GEMM + J^T J: 128x128, BK=32, counted-vmcnt 3-buffer pipeline ----
// Depth-2 lookahead: prologue stages tiles 0,1; tile T stages T+2 into buf (T+2)%3.
// Per tile: {vmcnt(4) [T's loads landed, T+1's may fly]; s_barrier; 8 ds_read;
//           stage T+2; 16 MFMA}. vmcnt hits 0 only at the last tile.
// LDS XOR swizzle (2-way clean): stored unit u_d = u_global ^ ((row>>1)&3); applied as
// pre-swizzled GLOBAL source (linear gload_lds dest, rule #21) + swizzled ds_read.
__global__ __launch_bounds__(256) void jtj_fused(
    const bf16* __restrict__ Vt, const bf16* __restrict__ W2t,
    float* __restrict__ S, int Mb, int b0)
{
    __shared__ union {
        struct { __align__(16) bf16 As[3][128 * 32]; __align__(16) bf16 Bs[3][128 * 32]; } s; // 48KB
        __align__(16) bf16 J[128 * 136];                                                       // 34.8KB
    } u;
    const int tid = threadIdx.x;
    const int w = tid >> 6, l = tid & 63;
    const int wr = w >> 1, wc = w & 1;

    int mb, nbk;
    if ((Mb & 7) == 0) {
        int lin = blockIdx.y * 24 + blockIdx.x;
        int xcd = lin & 7, idx = lin >> 3;
        int mchunk = Mb >> 3;
        mb = xcd * mchunk + idx / 24;
        nbk = idx % 24;
    } else { mb = blockIdx.y; nbk = blockIdx.x; }
    const int m0 = mb * 128, n0 = nbk * 128;

    f32x4v acc[4][4];
    #pragma unroll
    for (int a = 0; a < 4; ++a)
        #pragma unroll
        for (int b = 0; b < 4; ++b) acc[a][b] = (f32x4v){0.f, 0.f, 0.f, 0.f};

    // staging: thread t covers (row = t>>2, dest col-unit = t&3) of a 64-row unit.
    // source col-byte pre-swizzled: unit ^ ((row>>1)&3) = (t&3) ^ ((t>>3)&3)
    const int strow = tid >> 2;
    const int scb = (((tid & 3) ^ ((tid >> 3) & 3)) << 4);

    auto STAGE = [&](int kt, int bi) {
        const char* a0 = (const char*)Vt  + ((size_t)(m0 + strow) * H_ + kt * 32) * 2 + scb;
        const char* b0p = (const char*)W2t + ((size_t)(n0 + strow) * H_ + kt * 32) * 2 + scb;
        char* la = (char*)u.s.As[bi] + w * 1024;
        char* lb = (char*)u.s.Bs[bi] + w * 1024;
        gload_lds16(a0, la);
        gload_lds16(a0 + (size_t)64 * H_ * 2, la + 4096);
        gload_lds16(b0p, lb);
        gload_lds16(b0p + (size_t)64 * H_ * 2, lb + 4096);
    };

    // prologue: tiles 0 and 1
    STAGE(0, 0);
    STAGE(1, 1);

    // lane-static swizzled read col-byte: (l>>4) ^ ((row>>1)&3), row&7 bits from l&15
    const int rdcb = (((l >> 4) ^ ((l >> 1) & 3)) << 4);

    for (int kt = 0; kt < H_ / 32; ++kt) {
        __builtin_amdgcn_sched_barrier(0);
        if (kt == H_ / 32 - 1) asm volatile("s_waitcnt vmcnt(0)" ::: "memory");
        else                   asm volatile("s_waitcnt vmcnt(4)" ::: "memory");
        __builtin_amdgcn_s_barrier();
        __builtin_amdgcn_sched_barrier(0);
        const int cur = kt % 3;
        const char* Ab = (const char*)u.s.As[cur];
        const char* Bb = (const char*)u.s.Bs[cur];
        s16x8 af[4], bfr[4];
        #pragma unroll
        for (int mf = 0; mf < 4; ++mf)
            af[mf] = *(const s16x8*)(Ab + (wr * 64 + mf * 16 + (l & 15)) * 64 + rdcb);
        #pragma unroll
        for (int nf = 0; nf < 4; ++nf)
            bfr[nf] = *(const s16x8*)(Bb + (wc * 64 + nf * 16 + (l & 15)) * 64 + rdcb);
        if (kt + 2 < H_ / 32) STAGE(kt + 2, (kt + 2) % 3);
        #pragma unroll
        for (int mf = 0; mf < 4; ++mf)
            #pragma unroll
            for (int nf = 0; nf < 4; ++nf)
                acc[mf][nf] = __builtin_amdgcn_mfma_f32_16x16x32_bf16(af[mf], bfr[nf], acc[mf][nf], 0, 0, 0);
    }

    // ---- epilogue: J (bf16) -> LDS, per-strip self-product (round-5 proven form) ----
    __syncthreads();
    #pragma unroll
    for (int mf = 0; mf < 4; ++mf) {
        int rbase = wr * 64 + mf * 16 + (l >> 4) * 4;
        #pragma unroll
        for (int nf = 0; nf < 4; ++nf) {
            int col = wc * 64 + nf * 16 + (l & 15);
            #pragma unroll
            for (int r = 0; r < 4; ++r)
                u.J[(rbase + r) * 136 + col] = __float2bfloat16(acc[mf][nf][r]);
        }
    }
    __syncthreads();

    #pragma unroll
    for (int t2 = 0; t2 < 2; ++t2) {
        int bl = w * 2 + t2;
        f32x4v sp = (f32x4v){0.f, 0.f, 0.f, 0.f};
        #pragma unroll
        for (int kq = 0; kq < 4; ++kq) {
            s16x8 fr = *(const s16x8*)&u.J[(bl * 16 + (l & 15)) * 136 + kq * 32 + (l >> 4) * 8];
            sp = __builtin_amdgcn_mfma_f32_16x16x32_bf16(fr, fr, sp, 0, 0, 0);
        }
        int bglob = b0 + mb * 8 + bl;
        #pragma unroll
        for (int r = 0; r < 4; ++r)
            atomicAdd(&S[(size_t)bglob * 256 + ((l >> 4) * 4 + r) * 16 + (l & 15)], sp[r]);
    }
}

// ---------------- hessian via MFMA ----------------
__global__ __launch_bounds__(256) void hess_mfma(const float* __restrict__ t,
    const float* __restrict__ g, const bf16* __restrict__ W1b, float* __restrict__ S)
{
    const int w = threadIdx.x >> 6, l = threadIdx.x & 63;
    const int b = blockIdx.x * 4 + w;
    const int row = l & 15, kq = (l >> 4) * 8;

    f32x4v sp = (f32x4v){0.f, 0.f, 0.f, 0.f};
    for (int k0 = 0; k0 < H_; k0 += 32) {
        int kk = k0 + kq;
        s16x8 wf = *(const s16x8*)&W1b[(size_t)row * H_ + kk];
        float4 t0 = *(const float4*)&t[(size_t)b * H_ + kk];
        float4 t1 = *(const float4*)&t[(size_t)b * H_ + kk + 4];
        float4 g0 = *(const float4*)&g[(size_t)b * H_ + kk];
        float4 g1 = *(const float4*)&g[(size_t)b * H_ + kk + 4];
        float wv[8];
        wv[0] = 2.f * g0.x * t0.x * (1.f - t0.x * t0.x);
        wv[1] = 2.f * g0.y * t0.y * (1.f - t0.y * t0.y);
        wv[2] = 2.f * g0.z * t0.z * (1.f - t0.z * t0.z);
        wv[3] = 2.f * g0.w * t0.w * (1.f - t0.w * t0.w);
        wv[4] = 2.f * g1.x * t1.x * (1.f - t1.x * t1.x);
        wv[5] = 2.f * g1.y * t1.y * (1.f - t1.y * t1.y);
        wv[6] = 2.f * g1.z * t1.z * (1.f - t1.z * t1.z);
        wv[7] = 2.f * g1.w * t1.w * (1.f - t1.w * t1.w);
        union { s16x8 v; bf16 e[8]; } af;
        #pragma unroll
        for (int e = 0; e < 8; ++e)
            af.e[e] = __float2bfloat16(wv[e] * bf2f((unsigned short)wf[e]));
        sp = __builtin_amdgcn_mfma_f32_16x16x32_bf16(af.v, wf, sp, 0, 0, 0);
    }
    #pragma unroll
    for (int r = 0; r < 4; ++r)
        S[(size_t)b * 256 + ((l >> 4) * 4 + r) * 16 + (l & 15)] += sp[r];
}

// ---------------- fused prep: all casts in one launch ----------------
__global__ __launch_bounds__(256) void prep_all(
    const float* __restrict__ x, const float* __restrict__ enc_W1,
    const float* __restrict__ dec_W2, const float* __restrict__ dec_W1,
    bf16* __restrict__ x_bf, bf16* __restrict__ eW1t,
    bf16* __restrict__ W2t, bf16* __restrict__ W2b, bf16* __restrict__ W1b)
{
    __shared__ float tile[64][65];
    const int blk = blockIdx.x;
    const int tid = threadIdx.x;
    if (blk < 768) {
        int i = blk * 256 + tid;
        const float4* p = (const float4*)x + (size_t)i * 2;
        float4 a = p[0], b = p[1];
        union { s16x8 v; bf16 e[8]; } u;
        u.e[0] = __float2bfloat16(a.x); u.e[1] = __float2bfloat16(a.y);
        u.e[2] = __float2bfloat16(a.z); u.e[3] = __float2bfloat16(a.w);
        u.e[4] = __float2bfloat16(b.x); u.e[5] = __float2bfloat16(b.y);
        u.e[6] = __float2bfloat16(b.z); u.e[7] = __float2bfloat16(b.w);
        *(s16x8*)&x_bf[(size_t)i * 8] = u.v;
    } else if (blk < 768 + 1536) {
        int bid = blk - 768;
        int r0 = (bid % 48) * 64, c0 = (bid / 48) * 64;
        int tx = tid & 63, ty = tid >> 6;
        #pragma unroll
        for (int k = 0; k < 16; ++k) {
            int rr = ty * 16 + k;
            tile[rr][tx] = enc_W1[(size_t)(r0 + rr) * H_ + c0 + tx];
        }
        __syncthreads();
        #pragma unroll
        for (int k = 0; k < 16; ++k) {
            int cc = ty * 16 + k;
            eW1t[(size_t)(c0 + cc) * D_ + r0 + tx] = __float2bfloat16(tile[tx][cc]);
        }
    } else if (blk < 768 + 3072) {
        int bid = blk - 768 - 1536;
        int r0 = (bid % 32) * 64, c0 = (bid / 32) * 64;
        int tx = tid & 63, ty = tid >> 6;
        #pragma unroll
        for (int k = 0; k < 16; ++k) {
            int rr = ty * 16 + k;
            float v = dec_W2[(size_t)(r0 + rr) * D_ + c0 + tx];
            tile[rr][tx] = v;
            W2b[(size_t)(r0 + rr) * D_ + c0 + tx] = __float2bfloat16(v);
        }
        __syncthreads();
        #pragma unroll
        for (int k = 0; k < 16; ++k) {
            int cc = ty * 16 + k;
            W2t[(size_t)(c0 + cc) * H_ + r0 + tx] = __float2bfloat16(tile[tx][cc]);
        }
    } else {
        int i = (blk - 768 - 3072) * 256 + tid;
        if (i < N_ * H_ / 8) {
            const float4* p = (const float4*)dec_W1 + (size_t)i * 2;
            float4 a = p[0], b = p[1];
            union { s16x8 v; bf16 e[8]; } u;
            u.e[0] = __float2bfloat16(a.x); u.e[1] = __float2bfloat16(a.y);
            u.e[2] = __float2bfloat16(a.z); u.e[3] = __float2bfloat16(a.w);
            u.e[4] = __float2bfloat16(b.x); u.e[5] = __float2bfloat16(b.y);
            u.e[6] = __float2bfloat16(b.z); u.e[7] = __float2bfloat16(b.w);
            *(s16x8*)&W1b[(size_t)i * 8] = u.v;
        }
    }
}

// ---------------- zsig + build_t fused ----------------
__global__ __launch_bounds__(256) void zsig_t_kernel(const float* __restrict__ Ch,
    const float* __restrict__ enc_b1, const float* __restrict__ Wmu, const float* __restrict__ bmu,
    const float* __restrict__ Wls, const float* __restrict__ bls,
    const float* __restrict__ dW1, const float* __restrict__ db1,
    float* __restrict__ z_star, float* __restrict__ lsig, float* __restrict__ sigma,
    float* __restrict__ t, bf16* __restrict__ tb)
{
    const int b = blockIdx.x, tid = threadIdx.x;
    float acc[17];
    #pragma unroll
    for (int i = 0; i < 17; ++i) acc[i] = 0.f;
    for (int hh = tid; hh < H_; hh += 256) {
        float hv = tanhf(Ch[(size_t)b * H_ + hh] + enc_b1[hh]);
        const float* wr = &Wmu[(size_t)hh * 16];
        #pragma unroll
        for (int i = 0; i < 16; ++i) acc[i] += hv * wr[i];
        acc[16] += hv * Wls[hh];
    }
    __shared__ float red[17][4];
    __shared__ float zs[16];
    const int wid = tid >> 6, lane = tid & 63;
    #pragma unroll
    for (int i = 0; i < 17; ++i) {
        float v = acc[i];
        #pragma unroll
        for (int off = 32; off; off >>= 1) v += __shfl_xor(v, off);
        if (lane == 0) red[i][wid] = v;
    }
    __syncthreads();
    if (tid < 17) {
        float v = red[tid][0] + red[tid][1] + red[tid][2] + red[tid][3];
        if (tid < 16) { float z = v + bmu[tid]; zs[tid] = z; z_star[(size_t)b * 16 + tid] = z; }
        else { float ls = v + bls[0]; lsig[b] = ls; sigma[b] = expf(ls); }
    }
    __syncthreads();
    for (int hh = tid; hh < H_; hh += 256) {
        float a = db1[hh];
        #pragma unroll
        for (int i = 0; i < 16; ++i) a += zs[i] * dW1[(size_t)i * H_ + hh];
        float tv = tanhf(a);
        t[(size_t)b * H_ + hh] = tv;
        tb[(size_t)b * H_ + hh] = __float2bfloat16(tv);
    }
}

// t = tanh(z @ W1 + b1), bf16 out only
__global__ __launch_bounds__(256) void build_t(const float* __restrict__ z,
    const float* __restrict__ W1, const float* __restrict__ b1, bf16* __restrict__ tb)
{
    __shared__ float zs[16];
    int b = blockIdx.x, tid = threadIdx.x;
    if (tid < 16) zs[tid] = z[(size_t)b * 16 + tid];
    __syncthreads();
    for (int hh = tid; hh < H_; hh += 256) {
        float a = b1[hh];
        #pragma unroll
        for (int i = 0; i < 16; ++i) a += zs[i] * W1[(size_t)i * H_ + hh];
        tb[(size_t)b * H_ + hh] = __float2bfloat16(tanhf(a));
    }
}

// Vt[(b_local*16+i), h] = (1-t^2) * W1[i,h]  (bf16)
__global__ __launch_bounds__(256) void build_vt(const float* __restrict__ t,
    const float* __restrict__ W1, bf16* __restrict__ Vt, int b0)
{
    int bl = blockIdx.x, b = b0 + bl, tid = threadIdx.x;
    __shared__ float u[H_];
    for (int hh = tid; hh < H_; hh += 256) {
        float tv = t[(size_t)b * H_ + hh];
        u[hh] = 1.f - tv * tv;
    }
    __syncthreads();
    size_t base = (size_t)bl * 16 * H_;
    int hh = tid * 8;
    for (int i = 0; i < 16; ++i) {
        union { s16x8 v; bf16 e[8]; } pk;
        #pragma unroll
        for (int k = 0; k < 8; ++k)
            pk.e[k] = __float2bfloat16(u[hh + k] * W1[(size_t)i * H_ + hh + k]);
        *(s16x8*)&Vt[base + (size_t)i * H_ + hh] = pk.v;
    }
}

// ---------------- per-batch 16x16: barrier-free register solve ----------------
__global__ __launch_bounds__(64) void solve_kernel(const float* __restrict__ S,
    const float* __restrict__ sigma, const float* __restrict__ z_star,
    const float* __restrict__ eps, float* __restrict__ z_sample, float* __restrict__ d_out)
{
    const int lane = threadIdx.x;
    const int q = lane >> 4;
    const int j = lane & 15;
    const int b = blockIdx.x * 4 + q;

    const float sg = sigma[b];
    const float inv_s2 = 1.0f / (sg * sg);

    float a0[16], a[16];
    #pragma unroll
    for (int r = 0; r < 16; ++r) {
        a0[r] = S[(size_t)b * 256 + r * 16 + j] * inv_s2 + ((r == j) ? 1.0f : 0.0f);
        a[r] = a0[r];
    }

    #pragma unroll
    for (int k = 0; k < 14; ++k) {
        float x[16];
        #pragma unroll
        for (int r = 0; r < 16; ++r) x[r] = __shfl(a[k], r, 16);
        float sig2 = 0.f;
        #pragma unroll
        for (int r = 0; r < 16; ++r) if (r > k + 1) sig2 += x[r] * x[r];
        float x0 = x[k + 1];
        float normx = sqrtf(sig2 + x0 * x0);
        float alpha = (x0 >= 0.f) ? -normx : normx;
        float v[16];
        #pragma unroll
        for (int r = 0; r < 16; ++r)
            v[r] = (r <= k) ? 0.f : ((r == k + 1) ? x0 - alpha : x[r]);
        float vtv = 0.f;
        #pragma unroll
        for (int r = 0; r < 16; ++r) vtv += v[r] * v[r];
        float beta = (vtv > 1e-28f) ? 2.0f / vtv : 0.f;
        float sj = 0.f;
        #pragma unroll
        for (int r = 0; r < 16; ++r) sj += a[r] * v[r];
        float av[16];
        #pragma unroll
        for (int r = 0; r < 16; ++r) av[r] = __shfl(sj, r, 16);
        float vtav = 0.f;
        #pragma unroll
        for (int r = 0; r < 16; ++r) vtav += v[r] * av[r];
        float c = 0.5f * beta * vtav;
        float wv[16];
        #pragma unroll
        for (int r = 0; r < 16; ++r) wv[r] = beta * (av[r] - c * v[r]);
        float vj = (j <= k) ? 0.f : ((j == k + 1) ? a[k] - alpha : a[k]);
        float wj = beta * (sj - c * vj);
        #pragma unroll
        for (int r = 0; r < 16; ++r) a[r] -= v[r] * wj + wv[r] * vj;
    }

    float dg[16], eo[15];
    #pragma unroll
    for (int r = 0; r < 16; ++r) dg[r] = __shfl(a[r], r, 16);
    #pragma unroll
    for (int r = 0; r < 15; ++r) eo[r] = __shfl(a[r + 1], r, 16);

    float lo = 1e30f, hi = 1e30f;
    #pragma unroll
    for (int r = 0; r < 16; ++r) {
        float rad = ((r > 0) ? fabsf(eo[r - 1]) : 0.f) + ((r < 15) ? fabsf(eo[r]) : 0.f);
        lo = fminf(lo, dg[r] - rad);
        hi = fminf(hi, dg[r]);
    }
    lo -= 1e-4f; hi += 1e-4f;

    #pragma unroll
    for (int pass = 0; pass < 5; ++pass) {
        float step = (hi - lo) * (1.0f / 17.0f);
        float s = lo + step * (float)(j + 1);
        float qq = dg[0] - s;
        int cnt = (qq < 0.f) ? 1 : 0;
        #pragma unroll
        for (int i = 1; i < 16; ++i) {
            float denom = (fabsf(qq) < 1e-30f) ? -1e-30f : qq;
            qq = dg[i] - s - eo[i - 1] * eo[i - 1] / denom;
            cnt += (qq < 0.f) ? 1 : 0;
        }
        unsigned long long bal = __ballot(cnt >= 1);
        unsigned grp = (unsigned)((bal >> (q * 16)) & 0xffffull);
        int f = grp ? (__ffs(grp) - 1) : 16;
        float nlo = lo + step * (float)f;
        float nhi = (f < 16) ? (lo + step * (float)(f + 1)) : hi;
        lo = nlo; hi = nhi;
    }
    const float lam_min = 0.5f * (lo + hi);
    const float delta = 10.0f - lam_min;

    float bm[16];
    #pragma unroll
    for (int r = 0; r < 16; ++r) bm[r] = a0[r] + ((r == j) ? delta : 0.f);

    float ldsum = 0.f;
    #pragma unroll
    for (int kk = 0; kk < 16; ++kk) {
        float ck[16];
        #pragma unroll
        for (int r = 0; r < 16; ++r) ck[r] = __shfl(bm[kk], r, 16);
        float dkk = sqrtf(fmaxf(ck[kk], 1e-30f));
        float inv = 1.0f / dkk;
        ldsum += logf(dkk);
        float lfull[16];
        #pragma unroll
        for (int r = 0; r < 16; ++r) lfull[r] = ck[r] * inv;
        float lj = bm[kk] * inv;
        if (j == kk) {
            #pragma unroll
            for (int r = 0; r < 16; ++r) bm[r] = (r >= kk) ? lfull[r] : 0.f;
        } else if (j > kk) {
            #pragma unroll
            for (int r = 0; r < 16; ++r)
                if (r > kk) bm[r] -= lfull[r] * lj;
        }
    }

    float w[16];
    #pragma unroll
    for (int r = 0; r < 16; ++r) w[r] = 0.f;
    #pragma unroll
    for (int i = 0; i < 16; ++i) {
        float row[16];
        #pragma unroll
        for (int kx = 0; kx < 16; ++kx) row[kx] = __shfl(bm[i], kx, 16);
        float sacc = 0.f;
        #pragma unroll
        for (int kx = 0; kx < 16; ++kx) if (kx < i) sacc += row[kx] * w[kx];
        float invd = 1.0f / row[i];
        float val = (i == j) ? invd : (-sacc * invd);
        w[i] = (i >= j) ? val : 0.f;
    }

    float tsum = 0.f;
    #pragma unroll
    for (int r = 0; r < 16; ++r) tsum += w[r] * w[r];
    float zv = z_star[(size_t)b * 16 + j];
    float ep = eps[(size_t)b * 16 + j];
    float epsv[16];
    #pragma unroll
    for (int r = 0; r < 16; ++r) epsv[r] = __shfl(ep, r, 16);
    float zoff = 0.f;
    #pragma unroll
    for (int r = 0; r < 16; ++r) zoff += w[r] * epsv[r];
    z_sample[(size_t)b * 16 + j] = zv + zoff;

    float zsq = zv * zv;
    #pragma unroll
    for (int off = 1; off < 16; off <<= 1) {
        tsum += __shfl_xor(tsum, off);
        zsq  += __shfl_xor(zsq, off);
    }
    if (j == 0) {
        d_out[2 * 512 + b] = 0.5f * zsq + 0.5f * tsum;
        d_out[3 * 512 + b] = ldsum;
        d_out[4 * 512 + b] = sg;
    }
}

__global__ void finalize_kernel(const float* __restrict__ rlsum, const float* __restrict__ sigma,
    const float* __restrict__ lsig, float* __restrict__ d_out)
{
    int b = blockIdx.x * 256 + threadIdx.x;
    if (b < BS_) {
        float sg = sigma[b];
        float rl = rlsum[b] / (2.0f * sg * sg);
        float le = d_out[2 * 512 + b];
        float ld = d_out[3 * 512 + b];
        d_out[b] = (rl + le + ld) / 3072.0f + lsig[b];
        d_out[512 + b] = rl;
    }
}

extern "C" void kernel_launch(void* const* d_in, const int* in_sizes, int n_in,
                              void* d_out, int out_size, void* d_ws, size_t ws_size,
                              hipStream_t stream)
{
    const float* x       = (const float*)d_in[0];
    const float* eps     = (const float*)d_in[1];
    const float* enc_W1  = (const float*)d_in[2];
    const float* enc_b1  = (const float*)d_in[3];
    const float* enc_Wmu = (const float*)d_in[4];
    const float* enc_bmu = (const float*)d_in[5];
    const float* enc_Wls = (const float*)d_in[6];
    const float* enc_bls = (const float*)d_in[7];
    const float* dec_W1  = (const float*)d_in[8];
    const float* dec_b1  = (const float*)d_in[9];
    const float* dec_W2  = (const float*)d_in[10];
    const float* dec_b2  = (const float*)d_in[11];
    float* out = (float*)d_out;

    char* wsb = (char*)d_ws;
    size_t off = 0;
    auto alloc = [&](size_t bytes) -> void* {
        off = (off + 255) & ~(size_t)255;
        void* p = wsb + off;
        off += bytes;
        return p;
    };

    float* Ch   = (float*)alloc((size_t)BS_ * H_ * 4);
    float* Cd   = (float*)alloc((size_t)BS_ * D_ * 4);
    float* g    = (float*)alloc((size_t)BS_ * H_ * 4);
    float* S    = (float*)alloc((size_t)BS_ * 256 * 4);
    size_t zero_span = (size_t)((char*)(S + BS_ * 256) - (char*)Ch);

    float* t    = (float*)alloc((size_t)BS_ * H_ * 4);
    float* z_st = (float*)alloc((size_t)BS_ * 16 * 4);
    float* lsig = (float*)alloc(BS_ * 4);
    float* sigm = (float*)alloc(BS_ * 4);
    float* z_sm = (float*)alloc((size_t)BS_ * 16 * 4);
    float* rls  = (float*)alloc(BS_ * 4);
    bf16* x_bf  = (bf16*)alloc((size_t)BS_ * D_ * 2);
    bf16* eW1t  = (bf16*)alloc((size_t)H_ * D_ * 2);
    bf16* W2b   = (bf16*)alloc((size_t)H_ * D_ * 2);
    bf16* W2t   = (bf16*)alloc((size_t)D_ * H_ * 2);
    bf16* W1b   = (bf16*)alloc((size_t)N_ * H_ * 2);
    bf16* t_bf  = (bf16*)alloc((size_t)BS_ * H_ * 2);
    bf16* e_bf  = (bf16*)alloc((size_t)BS_ * D_ * 2);
    bf16* t2b   = (bf16*)alloc((size_t)BS_ * H_ * 2);

    int nb = 0;
    size_t base_off = off;
    const int cand[3] = {512, 128, 32};
    bf16* Vt = nullptr;
    for (int ci = 0; ci < 3; ++ci) {
        off = base_off;
        int n = cand[ci];
        bf16* vt = (bf16*)alloc((size_t)n * 16 * H_ * 2);
        if (off <= ws_size) { nb = n; Vt = vt; break; }
    }
    if (nb == 0) return;

    prep_all<<<dim3(768 + 3072 + 16), 256, 0, stream>>>(
        x, enc_W1, dec_W2, dec_W1, x_bf, eW1t, W2t, W2b, W1b);
    hipMemsetAsync(Ch, 0, zero_span, stream);

    mfma_nt_sk<<<dim3(H_ / 128, BS_ / 128, 4), 256, 0, stream>>>(
        x_bf, eW1t, Ch, BS_, H_, D_, D_ / 4);
    zsig_t_kernel<<<dim3(BS_), 256, 0, stream>>>(Ch, enc_b1, enc_Wmu, enc_bmu, enc_Wls, enc_bls,
        dec_W1, dec_b1, z_st, lsig, sigm, t, t_bf);
    mfma_nt_sk<<<dim3(D_ / 128, BS_ / 128, 4), 256, 0, stream>>>(
        t_bf, W2t, Cd, BS_, D_, H_, H_ / 4);
    ep_ebf<<<dim3(BS_ * D_ / 8 / 256), 256, 0, stream>>>(Cd, dec_b2, x, e_bf, BS_ * D_, D_);
    mfma_nt_sk<<<dim3(H_ / 128, BS_ / 128, 4), 256, 0, stream>>>(
        e_bf, W2b, g, BS_, H_, D_, D_ / 4);

    // S = J^T J (128x128 tile, counted-vmcnt 3-buffer pipeline, fused epilogue)
    for (int b0 = 0; b0 < BS_; b0 += nb) {
        build_vt<<<dim3(nb), 256, 0, stream>>>(t, dec_W1, Vt, b0);
        jtj_fused<<<dim3(D_ / 128, nb * 16 / 128), 256, 0, stream>>>(
            Vt, W2t, S, nb * 16 / 128, b0);
    }
    hess_mfma<<<dim3(BS_ / 4), 256, 0, stream>>>(t, g, W1b, S);

    solve_kernel<<<dim3(BS_ / 4), 64, 0, stream>>>(S, sigm, z_st, eps, z_sm, out);
    build_t<<<dim3(BS_), 256, 0, stream>>>(z_sm, dec_W1, dec_b1, t2b);
    hipMemsetAsync(Cd, 0, (size_t)BS_ * D_ * 4, stream);
    mfma_nt_sk<<<dim3(D_ / 128, BS_ / 128, 4), 256, 0, stream>>>(
        t2b, W2t, Cd, BS_, D_, H_, H_ / 4);
    ep_recon<<<dim3(BS_), 256, 0, stream>>>(Cd, dec_b2, x, rls);
    finalize_kernel<<<dim3(2), 256, 0, stream>>>(rls, sigm, lsig, out);
}

// Round 11
// 322.091 us; speedup vs baseline: 1.3901x; 1.1162x over previous
//
#include <hip/hip_runtime.h>
#include <hip/hip_bf16.h>
#include <math.h>

#define D_ 3072
#define H_ 2048
#define N_ 16
#define BS_ 512

typedef short s16x8 __attribute__((ext_vector_type(8)));
typedef float f32x4v __attribute__((ext_vector_type(4)));
typedef __hip_bfloat16 bf16;

__device__ __forceinline__ void gload_lds16(const void* g, void* l) {
    __builtin_amdgcn_global_load_lds((const __attribute__((address_space(1))) void*)g,
                                     (__attribute__((address_space(3))) void*)l, 16, 0, 0);
}

__device__ __forceinline__ float bf2f(unsigned short u) {
    unsigned v = (unsigned)u << 16; float f; __builtin_memcpy(&f, &v, 4); return f;
}

// ---------------- split-K NT GEMM, slab output: C[z][m][n] = partial ----------------
__global__ __launch_bounds__(256) void mfma_nt_slab(
    const bf16* __restrict__ A, const bf16* __restrict__ Bt,
    float* __restrict__ C, int M, int N, int K, int KC)
{
    __shared__ __align__(16) bf16 As[128 * 32];
    __shared__ __align__(16) bf16 Bs[128 * 32];
    const int tid = threadIdx.x;
    const int w = tid >> 6, l = tid & 63;
    const int wr = w >> 1, wc = w & 1;
    const int m0 = blockIdx.y * 128, n0 = blockIdx.x * 128;
    const int kbeg = blockIdx.z * KC;
    float* Cz = C + (size_t)blockIdx.z * M * N;

    f32x4v acc[4][4];
    #pragma unroll
    for (int a = 0; a < 4; ++a)
        #pragma unroll
        for (int b = 0; b < 4; ++b) acc[a][b] = (f32x4v){0.f, 0.f, 0.f, 0.f};

    const int srow = l >> 2;
    const int scol = (l & 3) * 8;

    for (int k0 = kbeg; k0 < kbeg + KC; k0 += 32) {
        #pragma unroll
        for (int q = 0; q < 2; ++q) {
            int r0 = w * 32 + q * 16;
            gload_lds16(&A[(size_t)(m0 + r0 + srow) * K + k0 + scol], &As[r0 * 32]);
            gload_lds16(&Bt[(size_t)(n0 + r0 + srow) * K + k0 + scol], &Bs[r0 * 32]);
        }
        __syncthreads();
        s16x8 af[4], bfr[4];
        #pragma unroll
        for (int mf = 0; mf < 4; ++mf)
            af[mf] = *(const s16x8*)&As[(wr * 64 + mf * 16 + (l & 15)) * 32 + (l >> 4) * 8];
        #pragma unroll
        for (int nf = 0; nf < 4; ++nf)
            bfr[nf] = *(const s16x8*)&Bs[(wc * 64 + nf * 16 + (l & 15)) * 32 + (l >> 4) * 8];
        #pragma unroll
        for (int mf = 0; mf < 4; ++mf)
            #pragma unroll
            for (int nf = 0; nf < 4; ++nf)
                acc[mf][nf] = __builtin_amdgcn_mfma_f32_16x16x32_bf16(af[mf], bfr[nf], acc[mf][nf], 0, 0, 0);
        __syncthreads();
    }

    #pragma unroll
    for (int mf = 0; mf < 4; ++mf)
        #pragma unroll
        for (int nf = 0; nf < 4; ++nf) {
            int n = n0 + wc * 64 + nf * 16 + (l & 15);
            #pragma unroll
            for (int r = 0; r < 4; ++r) {
                int m = m0 + wr * 64 + mf * 16 + (l >> 4) * 4 + r;
                Cz[(size_t)m * N + n] = acc[mf][nf][r];
            }
        }
}

// ---------------- split-K NT GEMM, atomic accumulate (g only) ----------------
__global__ __launch_bounds__(256) void mfma_nt_sk(
    const bf16* __restrict__ A, const bf16* __restrict__ Bt,
    float* __restrict__ C, int M, int N, int K, int KC)
{
    __shared__ __align__(16) bf16 As[128 * 32];
    __shared__ __align__(16) bf16 Bs[128 * 32];
    const int tid = threadIdx.x;
    const int w = tid >> 6, l = tid & 63;
    const int wr = w >> 1, wc = w & 1;
    const int m0 = blockIdx.y * 128, n0 = blockIdx.x * 128;
    const int kbeg = blockIdx.z * KC;

    f32x4v acc[4][4];
    #pragma unroll
    for (int a = 0; a < 4; ++a)
        #pragma unroll
        for (int b = 0; b < 4; ++b) acc[a][b] = (f32x4v){0.f, 0.f, 0.f, 0.f};

    const int srow = l >> 2;
    const int scol = (l & 3) * 8;

    for (int k0 = kbeg; k0 < kbeg + KC; k0 += 32) {
        #pragma unroll
        for (int q = 0; q < 2; ++q) {
            int r0 = w * 32 + q * 16;
            gload_lds16(&A[(size_t)(m0 + r0 + srow) * K + k0 + scol], &As[r0 * 32]);
            gload_lds16(&Bt[(size_t)(n0 + r0 + srow) * K + k0 + scol], &Bs[r0 * 32]);
        }
        __syncthreads();
        s16x8 af[4], bfr[4];
        #pragma unroll
        for (int mf = 0; mf < 4; ++mf)
            af[mf] = *(const s16x8*)&As[(wr * 64 + mf * 16 + (l & 15)) * 32 + (l >> 4) * 8];
        #pragma unroll
        for (int nf = 0; nf < 4; ++nf)
            bfr[nf] = *(const s16x8*)&Bs[(wc * 64 + nf * 16 + (l & 15)) * 32 + (l >> 4) * 8];
        #pragma unroll
        for (int mf = 0; mf < 4; ++mf)
            #pragma unroll
            for (int nf = 0; nf < 4; ++nf)
                acc[mf][nf] = __builtin_amdgcn_mfma_f32_16x16x32_bf16(af[mf], bfr[nf], acc[mf][nf], 0, 0, 0);
        __syncthreads();
    }

    #pragma unroll
    for (int mf = 0; mf < 4; ++mf)
        #pragma unroll
        for (int nf = 0; nf < 4; ++nf) {
            int n = n0 + wc * 64 + nf * 16 + (l & 15);
            #pragma unroll
            for (int r = 0; r < 4; ++r) {
                int m = m0 + wr * 64 + mf * 16 + (l >> 4) * 4 + r;
                atomicAdd(&C[(size_t)m * N + n], acc[mf][nf][r]);
            }
        }
}

// ---------------- e epilogue: sum 4 slabs, e = x - (v + b2), bf16 out ----------------
__global__ __launch_bounds__(256) void ep_ebf(const float* __restrict__ C4,
    const float* __restrict__ bias, const float* __restrict__ X,
    bf16* __restrict__ Eout, int MN, int N)
{
    const size_t SL = (size_t)MN;
    int base = (blockIdx.x * 256 + threadIdx.x) * 8;
    if (base < MN) {
        float4 c0 = *(const float4*)&C4[base];
        float4 c1 = *(const float4*)&C4[base + 4];
        float4 d0 = *(const float4*)&C4[SL + base];
        float4 d1 = *(const float4*)&C4[SL + base + 4];
        float4 e0 = *(const float4*)&C4[2*SL + base];
        float4 e1 = *(const float4*)&C4[2*SL + base + 4];
        float4 f0 = *(const float4*)&C4[3*SL + base];
        float4 f1 = *(const float4*)&C4[3*SL + base + 4];
        float4 x0 = *(const float4*)&X[base];
        float4 x1 = *(const float4*)&X[base + 4];
        int n = base % N;
        float4 b0 = *(const float4*)&bias[n];
        float4 b1 = *(const float4*)&bias[n + 4];
        union { s16x8 v; bf16 e[8]; } u;
        u.e[0] = __float2bfloat16(x0.x - (c0.x + d0.x + e0.x + f0.x + b0.x));
        u.e[1] = __float2bfloat16(x0.y - (c0.y + d0.y + e0.y + f0.y + b0.y));
        u.e[2] = __float2bfloat16(x0.z - (c0.z + d0.z + e0.z + f0.z + b0.z));
        u.e[3] = __float2bfloat16(x0.w - (c0.w + d0.w + e0.w + f0.w + b0.w));
        u.e[4] = __float2bfloat16(x1.x - (c1.x + d1.x + e1.x + f1.x + b1.x));
        u.e[5] = __float2bfloat16(x1.y - (c1.y + d1.y + e1.y + f1.y + b1.y));
        u.e[6] = __float2bfloat16(x1.z - (c1.z + d1.z + e1.z + f1.z + b1.z));
        u.e[7] = __float2bfloat16(x1.w - (c1.w + d1.w + e1.w + f1.w + b1.w));
        *(s16x8*)&Eout[base] = u.v;
    }
}

// ---------------- recon epilogue + finalize: rowsum of (sum slabs + b2 - x)^2 ----------------
__global__ __launch_bounds__(256) void ep_recon_fin(const float* __restrict__ C4,
    const float* __restrict__ bias, const float* __restrict__ X,
    const float* __restrict__ sigma, const float* __restrict__ lsig, float* __restrict__ d_out)
{
    const size_t SL = (size_t)BS_ * D_;
    int m = blockIdx.x;
    float s = 0.f;
    for (int n = threadIdx.x * 4; n < D_; n += 1024) {
        size_t i = (size_t)m * D_ + n;
        float4 c0 = *(const float4*)&C4[i];
        float4 c1 = *(const float4*)&C4[SL + i];
        float4 c2 = *(const float4*)&C4[2*SL + i];
        float4 c3 = *(const float4*)&C4[3*SL + i];
        float4 bb = *(const float4*)&bias[n];
        float4 xx = *(const float4*)&X[i];
        float v0 = c0.x + c1.x + c2.x + c3.x + bb.x - xx.x;
        float v1 = c0.y + c1.y + c2.y + c3.y + bb.y - xx.y;
        float v2 = c0.z + c1.z + c2.z + c3.z + bb.z - xx.z;
        float v3 = c0.w + c1.w + c2.w + c3.w + bb.w - xx.w;
        s += v0 * v0 + v1 * v1 + v2 * v2 + v3 * v3;
    }
    __shared__ float red[4];
    int wid = threadIdx.x >> 6, lane = threadIdx.x & 63;
    #pragma unroll
    for (int off = 32; off; off >>= 1) s += __shfl_xor(s, off);
    if (lane == 0) red[wid] = s;
    __syncthreads();
    if (threadIdx.x == 0) {
        float tot = red[0] + red[1] + red[2] + red[3];
        float sg = sigma[m];
        float rl = tot / (2.0f * sg * sg);
        float le = d_out[2 * 512 + m];
        float ld = d_out[3 * 512 + m];
        d_out[m] = (rl + le + ld) / 3072.0f + lsig[m];
        d_out[512 + m] = rl;
    }
}

// ---------------- fused J-GEMM + J^T J (round-10: counted-vmcnt 3-buffer + swizzle) ----
__global__ __launch_bounds__(256) void jtj_fused(
    const bf16* __restrict__ Vt, const bf16* __restrict__ W2t,
    float* __restrict__ S, int Mb, int b0)
{
    __shared__ union {
        struct { __align__(16) bf16 As[3][128 * 32]; __align__(16) bf16 Bs[3][128 * 32]; } s;
        __align__(16) bf16 J[128 * 136];
    } u;
    const int tid = threadIdx.x;
    const int w = tid >> 6, l = tid & 63;
    const int wr = w >> 1, wc = w & 1;

    int mb, nbk;
    if ((Mb & 7) == 0) {
        int lin = blockIdx.y * 24 + blockIdx.x;
        int xcd = lin & 7, idx = lin >> 3;
        int mchunk = Mb >> 3;
        mb = xcd * mchunk + idx / 24;
        nbk = idx % 24;
    } else { mb = blockIdx.y; nbk = blockIdx.x; }
    const int m0 = mb * 128, n0 = nbk * 128;

    f32x4v acc[4][4];
    #pragma unroll
    for (int a = 0; a < 4; ++a)
        #pragma unroll
        for (int b = 0; b < 4; ++b) acc[a][b] = (f32x4v){0.f, 0.f, 0.f, 0.f};

    const int strow = tid >> 2;
    const int scb = (((tid & 3) ^ ((tid >> 3) & 3)) << 4);

    auto STAGE = [&](int kt, int bi) {
        const char* a0 = (const char*)Vt  + ((size_t)(m0 + strow) * H_ + kt * 32) * 2 + scb;
        const char* b0p = (const char*)W2t + ((size_t)(n0 + strow) * H_ + kt * 32) * 2 + scb;
        char* la = (char*)u.s.As[bi] + w * 1024;
        char* lb = (char*)u.s.Bs[bi] + w * 1024;
        gload_lds16(a0, la);
        gload_lds16(a0 + (size_t)64 * H_ * 2, la + 4096);
        gload_lds16(b0p, lb);
        gload_lds16(b0p + (size_t)64 * H_ * 2, lb + 4096);
    };

    STAGE(0, 0);
    STAGE(1, 1);

    const int rdcb = (((l >> 4) ^ ((l >> 1) & 3)) << 4);

    for (int kt = 0; kt < H_ / 32; ++kt) {
        __builtin_amdgcn_sched_barrier(0);
        if (kt == H_ / 32 - 1) asm volatile("s_waitcnt vmcnt(0)" ::: "memory");
        else                   asm volatile("s_waitcnt vmcnt(4)" ::: "memory");
        __builtin_amdgcn_s_barrier();
        __builtin_amdgcn_sched_barrier(0);
        const int cur = kt % 3;
        const char* Ab = (const char*)u.s.As[cur];
        const char* Bb = (const char*)u.s.Bs[cur];
        s16x8 af[4], bfr[4];
        #pragma unroll
        for (int mf = 0; mf < 4; ++mf)
            af[mf] = *(const s16x8*)(Ab + (wr * 64 + mf * 16 + (l & 15)) * 64 + rdcb);
        #pragma unroll
        for (int nf = 0; nf < 4; ++nf)
            bfr[nf] = *(const s16x8*)(Bb + (wc * 64 + nf * 16 + (l & 15)) * 64 + rdcb);
        if (kt + 2 < H_ / 32) STAGE(kt + 2, (kt + 2) % 3);
        #pragma unroll
        for (int mf = 0; mf < 4; ++mf)
            #pragma unroll
            for (int nf = 0; nf < 4; ++nf)
                acc[mf][nf] = __builtin_amdgcn_mfma_f32_16x16x32_bf16(af[mf], bfr[nf], acc[mf][nf], 0, 0, 0);
    }

    __syncthreads();
    #pragma unroll
    for (int mf = 0; mf < 4; ++mf) {
        int rbase = wr * 64 + mf * 16 + (l >> 4) * 4;
        #pragma unroll
        for (int nf = 0; nf < 4; ++nf) {
            int col = wc * 64 + nf * 16 + (l & 15);
            #pragma unroll
            for (int r = 0; r < 4; ++r)
                u.J[(rbase + r) * 136 + col] = __float2bfloat16(acc[mf][nf][r]);
        }
    }
    __syncthreads();

    #pragma unroll
    for (int t2 = 0; t2 < 2; ++t2) {
        int bl = w * 2 + t2;
        f32x4v sp = (f32x4v){0.f, 0.f, 0.f, 0.f};
        #pragma unroll
        for (int kq = 0; kq < 4; ++kq) {
            s16x8 fr = *(const s16x8*)&u.J[(bl * 16 + (l & 15)) * 136 + kq * 32 + (l >> 4) * 8];
            sp = __builtin_amdgcn_mfma_f32_16x16x32_bf16(fr, fr, sp, 0, 0, 0);
        }
        int bglob = b0 + mb * 8 + bl;
        #pragma unroll
        for (int r = 0; r < 4; ++r)
            atomicAdd(&S[(size_t)bglob * 256 + ((l >> 4) * 4 + r) * 16 + (l & 15)], sp[r]);
    }
}

// ---------------- hessian via MFMA ----------------
__global__ __launch_bounds__(256) void hess_mfma(const float* __restrict__ t,
    const float* __restrict__ g, const bf16* __restrict__ W1b, float* __restrict__ S)
{
    const int w = threadIdx.x >> 6, l = threadIdx.x & 63;
    const int b = blockIdx.x * 4 + w;
    const int row = l & 15, kq = (l >> 4) * 8;

    f32x4v sp = (f32x4v){0.f, 0.f, 0.f, 0.f};
    for (int k0 = 0; k0 < H_; k0 += 32) {
        int kk = k0 + kq;
        s16x8 wf = *(const s16x8*)&W1b[(size_t)row * H_ + kk];
        float4 t0 = *(const float4*)&t[(size_t)b * H_ + kk];
        float4 t1 = *(const float4*)&t[(size_t)b * H_ + kk + 4];
        float4 g0 = *(const float4*)&g[(size_t)b * H_ + kk];
        float4 g1 = *(const float4*)&g[(size_t)b * H_ + kk + 4];
        float wv[8];
        wv[0] = 2.f * g0.x * t0.x * (1.f - t0.x * t0.x);
        wv[1] = 2.f * g0.y * t0.y * (1.f - t0.y * t0.y);
        wv[2] = 2.f * g0.z * t0.z * (1.f - t0.z * t0.z);
        wv[3] = 2.f * g0.w * t0.w * (1.f - t0.w * t0.w);
        wv[4] = 2.f * g1.x * t1.x * (1.f - t1.x * t1.x);
        wv[5] = 2.f * g1.y * t1.y * (1.f - t1.y * t1.y);
        wv[6] = 2.f * g1.z * t1.z * (1.f - t1.z * t1.z);
        wv[7] = 2.f * g1.w * t1.w * (1.f - t1.w * t1.w);
        union { s16x8 v; bf16 e[8]; } af;
        #pragma unroll
        for (int e = 0; e < 8; ++e)
            af.e[e] = __float2bfloat16(wv[e] * bf2f((unsigned short)wf[e]));
        sp = __builtin_amdgcn_mfma_f32_16x16x32_bf16(af.v, wf, sp, 0, 0, 0);
    }
    #pragma unroll
    for (int r = 0; r < 4; ++r)
        S[(size_t)b * 256 + ((l >> 4) * 4 + r) * 16 + (l & 15)] += sp[r];
}

// ---------------- fused prep: all casts in one launch ----------------
__global__ __launch_bounds__(256) void prep_all(
    const float* __restrict__ x, const float* __restrict__ enc_W1,
    const float* __restrict__ dec_W2, const float* __restrict__ dec_W1,
    bf16* __restrict__ x_bf, bf16* __restrict__ eW1t,
    bf16* __restrict__ W2t, bf16* __restrict__ W2b, bf16* __restrict__ W1b)
{
    __shared__ float tile[64][65];
    const int blk = blockIdx.x;
    const int tid = threadIdx.x;
    if (blk < 768) {
        int i = blk * 256 + tid;
        const float4* p = (const float4*)x + (size_t)i * 2;
        float4 a = p[0], b = p[1];
        union { s16x8 v; bf16 e[8]; } u;
        u.e[0] = __float2bfloat16(a.x); u.e[1] = __float2bfloat16(a.y);
        u.e[2] = __float2bfloat16(a.z); u.e[3] = __float2bfloat16(a.w);
        u.e[4] = __float2bfloat16(b.x); u.e[5] = __float2bfloat16(b.y);
        u.e[6] = __float2bfloat16(b.z); u.e[7] = __float2bfloat16(b.w);
        *(s16x8*)&x_bf[(size_t)i * 8] = u.v;
    } else if (blk < 768 + 1536) {
        int bid = blk - 768;
        int r0 = (bid % 48) * 64, c0 = (bid / 48) * 64;
        int tx = tid & 63, ty = tid >> 6;
        #pragma unroll
        for (int k = 0; k < 16; ++k) {
            int rr = ty * 16 + k;
            tile[rr][tx] = enc_W1[(size_t)(r0 + rr) * H_ + c0 + tx];
        }
        __syncthreads();
        #pragma unroll
        for (int k = 0; k < 16; ++k) {
            int cc = ty * 16 + k;
            eW1t[(size_t)(c0 + cc) * D_ + r0 + tx] = __float2bfloat16(tile[tx][cc]);
        }
    } else if (blk < 768 + 3072) {
        int bid = blk - 768 - 1536;
        int r0 = (bid % 32) * 64, c0 = (bid / 32) * 64;
        int tx = tid & 63, ty = tid >> 6;
        #pragma unroll
        for (int k = 0; k < 16; ++k) {
            int rr = ty * 16 + k;
            float v = dec_W2[(size_t)(r0 + rr) * D_ + c0 + tx];
            tile[rr][tx] = v;
            W2b[(size_t)(r0 + rr) * D_ + c0 + tx] = __float2bfloat16(v);
        }
        __syncthreads();
        #pragma unroll
        for (int k = 0; k < 16; ++k) {
            int cc = ty * 16 + k;
            W2t[(size_t)(c0 + cc) * H_ + r0 + tx] = __float2bfloat16(tile[tx][cc]);
        }
    } else {
        int i = (blk - 768 - 3072) * 256 + tid;
        if (i < N_ * H_ / 8) {
            const float4* p = (const float4*)dec_W1 + (size_t)i * 2;
            float4 a = p[0], b = p[1];
            union { s16x8 v; bf16 e[8]; } u;
            u.e[0] = __float2bfloat16(a.x); u.e[1] = __float2bfloat16(a.y);
            u.e[2] = __float2bfloat16(a.z); u.e[3] = __float2bfloat16(a.w);
            u.e[4] = __float2bfloat16(b.x); u.e[5] = __float2bfloat16(b.y);
            u.e[6] = __float2bfloat16(b.z); u.e[7] = __float2bfloat16(b.w);
            *(s16x8*)&W1b[(size_t)i * 8] = u.v;
        }
    }
}

// ---------------- zsig + build_t + build_vt fused ----------------
__global__ __launch_bounds__(256) void zsig_t_kernel(const float* __restrict__ Ch4,
    const float* __restrict__ enc_b1, const float* __restrict__ Wmu, const float* __restrict__ bmu,
    const float* __restrict__ Wls, const float* __restrict__ bls,
    const float* __restrict__ dW1, const float* __restrict__ db1,
    float* __restrict__ z_star, float* __restrict__ lsig, float* __restrict__ sigma,
    float* __restrict__ t, bf16* __restrict__ tb, bf16* __restrict__ Vt)
{
    const int b = blockIdx.x, tid = threadIdx.x;
    const size_t SL = (size_t)BS_ * H_;
    float acc[17];
    #pragma unroll
    for (int i = 0; i < 17; ++i) acc[i] = 0.f;
    for (int hh = tid; hh < H_; hh += 256) {
        size_t idx = (size_t)b * H_ + hh;
        float c = Ch4[idx] + Ch4[SL + idx] + Ch4[2*SL + idx] + Ch4[3*SL + idx];
        float hv = tanhf(c + enc_b1[hh]);
        const float* wr = &Wmu[(size_t)hh * 16];
        #pragma unroll
        for (int i = 0; i < 16; ++i) acc[i] += hv * wr[i];
        acc[16] += hv * Wls[hh];
    }
    __shared__ float red[17][4];
    __shared__ float zs[16];
    __shared__ float us[H_];
    const int wid = tid >> 6, lane = tid & 63;
    #pragma unroll
    for (int i = 0; i < 17; ++i) {
        float v = acc[i];
        #pragma unroll
        for (int off = 32; off; off >>= 1) v += __shfl_xor(v, off);
        if (lane == 0) red[i][wid] = v;
    }
    __syncthreads();
    if (tid < 17) {
        float v = red[tid][0] + red[tid][1] + red[tid][2] + red[tid][3];
        if (tid < 16) { float z = v + bmu[tid]; zs[tid] = z; z_star[(size_t)b * 16 + tid] = z; }
        else { float ls = v + bls[0]; lsig[b] = ls; sigma[b] = expf(ls); }
    }
    __syncthreads();
    for (int hh = tid; hh < H_; hh += 256) {
        float a = db1[hh];
        #pragma unroll
        for (int i = 0; i < 16; ++i) a += zs[i] * dW1[(size_t)i * H_ + hh];
        float tv = tanhf(a);
        t[(size_t)b * H_ + hh] = tv;
        tb[(size_t)b * H_ + hh] = __float2bfloat16(tv);
        us[hh] = 1.f - tv * tv;
    }
    if (Vt) {
        __syncthreads();
        size_t base = (size_t)b * 16 * H_;
        int hh = tid * 8;
        for (int i = 0; i < 16; ++i) {
            union { s16x8 v; bf16 e[8]; } pk;
            #pragma unroll
            for (int k = 0; k < 8; ++k)
                pk.e[k] = __float2bfloat16(us[hh + k] * dW1[(size_t)i * H_ + hh + k]);
            *(s16x8*)&Vt[base + (size_t)i * H_ + hh] = pk.v;
        }
    }
}

// t = tanh(z @ W1 + b1), bf16 out only
__global__ __launch_bounds__(256) void build_t(const float* __restrict__ z,
    const float* __restrict__ W1, const float* __restrict__ b1, bf16* __restrict__ tb)
{
    __shared__ float zs[16];
    int b = blockIdx.x, tid = threadIdx.x;
    if (tid < 16) zs[tid] = z[(size_t)b * 16 + tid];
    __syncthreads();
    for (int hh = tid; hh < H_; hh += 256) {
        float a = b1[hh];
        #pragma unroll
        for (int i = 0; i < 16; ++i) a += zs[i] * W1[(size_t)i * H_ + hh];
        tb[(size_t)b * H_ + hh] = __float2bfloat16(tanhf(a));
    }
}

// Vt chunk builder (fallback path when workspace forces chunking)
__global__ __launch_bounds__(256) void build_vt(const float* __restrict__ t,
    const float* __restrict__ W1, bf16* __restrict__ Vt, int b0)
{
    int bl = blockIdx.x, b = b0 + bl, tid = threadIdx.x;
    __shared__ float u[H_];
    for (int hh = tid; hh < H_; hh += 256) {
        float tv = t[(size_t)b * H_ + hh];
        u[hh] = 1.f - tv * tv;
    }
    __syncthreads();
    size_t base = (size_t)bl * 16 * H_;
    int hh = tid * 8;
    for (int i = 0; i < 16; ++i) {
        union { s16x8 v; bf16 e[8]; } pk;
        #pragma unroll
        for (int k = 0; k < 8; ++k)
            pk.e[k] = __float2bfloat16(u[hh + k] * W1[(size_t)i * H_ + hh + k]);
        *(s16x8*)&Vt[base + (size_t)i * H_ + hh] = pk.v;
    }
}

// ---------------- per-batch 16x16: barrier-free register solve ----------------
__global__ __launch_bounds__(64) void solve_kernel(const float* __restrict__ S,
    const float* __restrict__ sigma, const float* __restrict__ z_star,
    const float* __restrict__ eps, float* __restrict__ z_sample, float* __restrict__ d_out)
{
    const int lane = threadIdx.x;
    const int q = lane >> 4;
    const int j = lane & 15;
    const int b = blockIdx.x * 4 + q;

    const float sg = sigma[b];
    const float inv_s2 = 1.0f / (sg * sg);

    float a0[16], a[16];
    #pragma unroll
    for (int r = 0; r < 16; ++r) {
        a0[r] = S[(size_t)b * 256 + r * 16 + j] * inv_s2 + ((r == j) ? 1.0f : 0.0f);
        a[r] = a0[r];
    }

    #pragma unroll
    for (int k = 0; k < 14; ++k) {
        float x[16];
        #pragma unroll
        for (int r = 0; r < 16; ++r) x[r] = __shfl(a[k], r, 16);
        float sig2 = 0.f;
        #pragma unroll
        for (int r = 0; r < 16; ++r) if (r > k + 1) sig2 += x[r] * x[r];
        float x0 = x[k + 1];
        float normx = sqrtf(sig2 + x0 * x0);
        float alpha = (x0 >= 0.f) ? -normx : normx;
        float v[16];
        #pragma unroll
        for (int r = 0; r < 16; ++r)
            v[r] = (r <= k) ? 0.f : ((r == k + 1) ? x0 - alpha : x[r]);
        float vtv = 0.f;
        #pragma unroll
        for (int r = 0; r < 16; ++r) vtv += v[r] * v[r];
        float beta = (vtv > 1e-28f) ? 2.0f / vtv : 0.f;
        float sj = 0.f;
        #pragma unroll
        for (int r = 0; r < 16; ++r) sj += a[r] * v[r];
        float av[16];
        #pragma unroll
        for (int r = 0; r < 16; ++r) av[r] = __shfl(sj, r, 16);
        float vtav = 0.f;
        #pragma unroll
        for (int r = 0; r < 16; ++r) vtav += v[r] * av[r];
        float c = 0.5f * beta * vtav;
        float wv[16];
        #pragma unroll
        for (int r = 0; r < 16; ++r) wv[r] = beta * (av[r] - c * v[r]);
        float vj = (j <= k) ? 0.f : ((j == k + 1) ? a[k] - alpha : a[k]);
        float wj = beta * (sj - c * vj);
        #pragma unroll
        for (int r = 0; r < 16; ++r) a[r] -= v[r] * wj + wv[r] * vj;
    }

    float dg[16], eo[15];
    #pragma unroll
    for (int r = 0; r < 16; ++r) dg[r] = __shfl(a[r], r, 16);
    #pragma unroll
    for (int r = 0; r < 15; ++r) eo[r] = __shfl(a[r + 1], r, 16);

    float lo = 1e30f, hi = 1e30f;
    #pragma unroll
    for (int r = 0; r < 16; ++r) {
        float rad = ((r > 0) ? fabsf(eo[r - 1]) : 0.f) + ((r < 15) ? fabsf(eo[r]) : 0.f);
        lo = fminf(lo, dg[r] - rad);
        hi = fminf(hi, dg[r]);
    }
    lo -= 1e-4f; hi += 1e-4f;

    #pragma unroll
    for (int pass = 0; pass < 5; ++pass) {
        float step = (hi - lo) * (1.0f / 17.0f);
        float s = lo + step * (float)(j + 1);
        float qq = dg[0] - s;
        int cnt = (qq < 0.f) ? 1 : 0;
        #pragma unroll
        for (int i = 1; i < 16; ++i) {
            float denom = (fabsf(qq) < 1e-30f) ? -1e-30f : qq;
            qq = dg[i] - s - eo[i - 1] * eo[i - 1] / denom;
            cnt += (qq < 0.f) ? 1 : 0;
        }
        unsigned long long bal = __ballot(cnt >= 1);
        unsigned grp = (unsigned)((bal >> (q * 16)) & 0xffffull);
        int f = grp ? (__ffs(grp) - 1) : 16;
        float nlo = lo + step * (float)f;
        float nhi = (f < 16) ? (lo + step * (float)(f + 1)) : hi;
        lo = nlo; hi = nhi;
    }
    const float lam_min = 0.5f * (lo + hi);
    const float delta = 10.0f - lam_min;

    float bm[16];
    #pragma unroll
    for (int r = 0; r < 16; ++r) bm[r] = a0[r] + ((r == j) ? delta : 0.f);

    float ldsum = 0.f;
    #pragma unroll
    for (int kk = 0; kk < 16; ++kk) {
        float ck[16];
        #pragma unroll
        for (int r = 0; r < 16; ++r) ck[r] = __shfl(bm[kk], r, 16);
        float dkk = sqrtf(fmaxf(ck[kk], 1e-30f));
        float inv = 1.0f / dkk;
        ldsum += logf(dkk);
        float lfull[16];
        #pragma unroll
        for (int r = 0; r < 16; ++r) lfull[r] = ck[r] * inv;
        float lj = bm[kk] * inv;
        if (j == kk) {
            #pragma unroll
            for (int r = 0; r < 16; ++r) bm[r] = (r >= kk) ? lfull[r] : 0.f;
        } else if (j > kk) {
            #pragma unroll
            for (int r = 0; r < 16; ++r)
                if (r > kk) bm[r] -= lfull[r] * lj;
        }
    }

    float w[16];
    #pragma unroll
    for (int r = 0; r < 16; ++r) w[r] = 0.f;
    #pragma unroll
    for (int i = 0; i < 16; ++i) {
        float row[16];
        #pragma unroll
        for (int kx = 0; kx < 16; ++kx) row[kx] = __shfl(bm[i], kx, 16);
        float sacc = 0.f;
        #pragma unroll
        for (int kx = 0; kx < 16; ++kx) if (kx < i) sacc += row[kx] * w[kx];
        float invd = 1.0f / row[i];
        float val = (i == j) ? invd : (-sacc * invd);
        w[i] = (i >= j) ? val : 0.f;
    }

    float tsum = 0.f;
    #pragma unroll
    for (int r = 0; r < 16; ++r) tsum += w[r] * w[r];
    float zv = z_star[(size_t)b * 16 + j];
    float ep = eps[(size_t)b * 16 + j];
    float epsv[16];
    #pragma unroll
    for (int r = 0; r < 16; ++r) epsv[r] = __shfl(ep, r, 16);
    float zoff = 0.f;
    #pragma unroll
    for (int r = 0; r < 16; ++r) zoff += w[r] * epsv[r];
    z_sample[(size_t)b * 16 + j] = zv + zoff;

    float zsq = zv * zv;
    #pragma unroll
    for (int off = 1; off < 16; off <<= 1) {
        tsum += __shfl_xor(tsum, off);
        zsq  += __shfl_xor(zsq, off);
    }
    if (j == 0) {
        d_out[2 * 512 + b] = 0.5f * zsq + 0.5f * tsum;
        d_out[3 * 512 + b] = ldsum;
        d_out[4 * 512 + b] = sg;
    }
}

extern "C" void kernel_launch(void* const* d_in, const int* in_sizes, int n_in,
                              void* d_out, int out_size, void* d_ws, size_t ws_size,
                              hipStream_t stream)
{
    const float* x       = (const float*)d_in[0];
    const float* eps     = (const float*)d_in[1];
    const float* enc_W1  = (const float*)d_in[2];
    const float* enc_b1  = (const float*)d_in[3];
    const float* enc_Wmu = (const float*)d_in[4];
    const float* enc_bmu = (const float*)d_in[5];
    const float* enc_Wls = (const float*)d_in[6];
    const float* enc_bls = (const float*)d_in[7];
    const float* dec_W1  = (const float*)d_in[8];
    const float* dec_b1  = (const float*)d_in[9];
    const float* dec_W2  = (const float*)d_in[10];
    const float* dec_b2  = (const float*)d_in[11];
    float* out = (float*)d_out;

    char* wsb = (char*)d_ws;
    size_t off = 0;
    auto alloc = [&](size_t bytes) -> void* {
        off = (off + 255) & ~(size_t)255;
        void* p = wsb + off;
        off += bytes;
        return p;
    };

    // contiguous zero region: g (4 MB) + S (0.5 MB)
    float* g    = (float*)alloc((size_t)BS_ * H_ * 4);
    float* S    = (float*)alloc((size_t)BS_ * 256 * 4);
    size_t zero_span = (size_t)((char*)(S + BS_ * 256) - (char*)g);

    float* Ch4  = (float*)alloc((size_t)4 * BS_ * H_ * 4);   // h split-K slabs (16 MB)
    float* Cd4  = (float*)alloc((size_t)4 * BS_ * D_ * 4);   // e/recon split-K slabs (24 MB)
    float* t    = (float*)alloc((size_t)BS_ * H_ * 4);
    float* z_st = (float*)alloc((size_t)BS_ * 16 * 4);
    float* lsig = (float*)alloc(BS_ * 4);
    float* sigm = (float*)alloc(BS_ * 4);
    float* z_sm = (float*)alloc((size_t)BS_ * 16 * 4);
    bf16* x_bf  = (bf16*)alloc((size_t)BS_ * D_ * 2);
    bf16* eW1t  = (bf16*)alloc((size_t)H_ * D_ * 2);
    bf16* W2b   = (bf16*)alloc((size_t)H_ * D_ * 2);
    bf16* W2t   = (bf16*)alloc((size_t)D_ * H_ * 2);
    bf16* W1b   = (bf16*)alloc((size_t)N_ * H_ * 2);
    bf16* t_bf  = (bf16*)alloc((size_t)BS_ * H_ * 2);
    bf16* e_bf  = (bf16*)alloc((size_t)BS_ * D_ * 2);
    bf16* t2b   = (bf16*)alloc((size_t)BS_ * H_ * 2);

    int nb = 0;
    size_t base_off = off;
    const int cand[3] = {512, 128, 32};
    bf16* Vt = nullptr;
    for (int ci = 0; ci < 3; ++ci) {
        off = base_off;
        int n = cand[ci];
        bf16* vt = (bf16*)alloc((size_t)n * 16 * H_ * 2);
        if (off <= ws_size) { nb = n; Vt = vt; break; }
    }
    if (nb == 0) return;
    bf16* Vt_full = (nb == 512) ? Vt : nullptr;

    prep_all<<<dim3(768 + 3072 + 16), 256, 0, stream>>>(
        x, enc_W1, dec_W2, dec_W1, x_bf, eW1t, W2t, W2b, W1b);
    hipMemsetAsync(g, 0, zero_span, stream);

    // h partials (slabs) -> zsig (+t, +Vt when full)
    mfma_nt_slab<<<dim3(H_ / 128, BS_ / 128, 4), 256, 0, stream>>>(
        x_bf, eW1t, Ch4, BS_, H_, D_, D_ / 4);
    zsig_t_kernel<<<dim3(BS_), 256, 0, stream>>>(Ch4, enc_b1, enc_Wmu, enc_bmu, enc_Wls, enc_bls,
        dec_W1, dec_b1, z_st, lsig, sigm, t, t_bf, Vt_full);
    // e partials (slabs) -> e_bf
    mfma_nt_slab<<<dim3(D_ / 128, BS_ / 128, 4), 256, 0, stream>>>(
        t_bf, W2t, Cd4, BS_, D_, H_, H_ / 4);
    ep_ebf<<<dim3(BS_ * D_ / 8 / 256), 256, 0, stream>>>(Cd4, dec_b2, x, e_bf, BS_ * D_, D_);
    // g = e @ W2^T (atomic accumulate)
    mfma_nt_sk<<<dim3(H_ / 128, BS_ / 128, 4), 256, 0, stream>>>(
        e_bf, W2b, g, BS_, H_, D_, D_ / 4);

    // S = J^T J
    if (Vt_full) {
        jtj_fused<<<dim3(D_ / 128, 512 * 16 / 128), 256, 0, stream>>>(
            Vt_full, W2t, S, 512 * 16 / 128, 0);
    } else {
        for (int b0 = 0; b0 < BS_; b0 += nb) {
            build_vt<<<dim3(nb), 256, 0, stream>>>(t, dec_W1, Vt, b0);
            jtj_fused<<<dim3(D_ / 128, nb * 16 / 128), 256, 0, stream>>>(
                Vt, W2t, S, nb * 16 / 128, b0);
        }
    }
    hess_mfma<<<dim3(BS_ / 4), 256, 0, stream>>>(t, g, W1b, S);

    solve_kernel<<<dim3(BS_ / 4), 64, 0, stream>>>(S, sigm, z_st, eps, z_sm, out);
    build_t<<<dim3(BS_), 256, 0, stream>>>(z_sm, dec_W1, dec_b1, t2b);
    // recon partials (slabs, reuse Cd4) -> fused rowsum + finalize
    mfma_nt_slab<<<dim3(D_ / 128, BS_ / 128, 4), 256, 0, stream>>>(
        t2b, W2t, Cd4, BS_, D_, H_, H_ / 4);
    ep_recon_fin<<<dim3(BS_), 256, 0, stream>>>(Cd4, dec_b2, x, sigm, lsig, out);
}

// Round 12
// 310.420 us; speedup vs baseline: 1.4424x; 1.0376x over previous
//
#include <hip/hip_runtime.h>
#include <hip/hip_bf16.h>
#include <math.h>

#define D_ 3072
#define H_ 2048
#define N_ 16
#define BS_ 512
#define NSL_ 8   // split-K slabs

typedef short s16x8 __attribute__((ext_vector_type(8)));
typedef float f32x4v __attribute__((ext_vector_type(4)));
typedef __hip_bfloat16 bf16;

__device__ __forceinline__ void gload_lds16(const void* g, void* l) {
    __builtin_amdgcn_global_load_lds((const __attribute__((address_space(1))) void*)g,
                                     (__attribute__((address_space(3))) void*)l, 16, 0, 0);
}

__device__ __forceinline__ float bf2f(unsigned short u) {
    unsigned v = (unsigned)u << 16; float f; __builtin_memcpy(&f, &v, 4); return f;
}

// ---------------- split-K NT GEMM, slab output: C[z][m][n] = partial ----------------
__global__ __launch_bounds__(256) void mfma_nt_slab(
    const bf16* __restrict__ A, const bf16* __restrict__ Bt,
    float* __restrict__ C, int M, int N, int K, int KC)
{
    __shared__ __align__(16) bf16 As[128 * 32];
    __shared__ __align__(16) bf16 Bs[128 * 32];
    const int tid = threadIdx.x;
    const int w = tid >> 6, l = tid & 63;
    const int wr = w >> 1, wc = w & 1;
    const int m0 = blockIdx.y * 128, n0 = blockIdx.x * 128;
    const int kbeg = blockIdx.z * KC;
    float* Cz = C + (size_t)blockIdx.z * M * N;

    f32x4v acc[4][4];
    #pragma unroll
    for (int a = 0; a < 4; ++a)
        #pragma unroll
        for (int b = 0; b < 4; ++b) acc[a][b] = (f32x4v){0.f, 0.f, 0.f, 0.f};

    const int srow = l >> 2;
    const int scol = (l & 3) * 8;

    for (int k0 = kbeg; k0 < kbeg + KC; k0 += 32) {
        #pragma unroll
        for (int q = 0; q < 2; ++q) {
            int r0 = w * 32 + q * 16;
            gload_lds16(&A[(size_t)(m0 + r0 + srow) * K + k0 + scol], &As[r0 * 32]);
            gload_lds16(&Bt[(size_t)(n0 + r0 + srow) * K + k0 + scol], &Bs[r0 * 32]);
        }
        __syncthreads();
        s16x8 af[4], bfr[4];
        #pragma unroll
        for (int mf = 0; mf < 4; ++mf)
            af[mf] = *(const s16x8*)&As[(wr * 64 + mf * 16 + (l & 15)) * 32 + (l >> 4) * 8];
        #pragma unroll
        for (int nf = 0; nf < 4; ++nf)
            bfr[nf] = *(const s16x8*)&Bs[(wc * 64 + nf * 16 + (l & 15)) * 32 + (l >> 4) * 8];
        #pragma unroll
        for (int mf = 0; mf < 4; ++mf)
            #pragma unroll
            for (int nf = 0; nf < 4; ++nf)
                acc[mf][nf] = __builtin_amdgcn_mfma_f32_16x16x32_bf16(af[mf], bfr[nf], acc[mf][nf], 0, 0, 0);
        __syncthreads();
    }

    #pragma unroll
    for (int mf = 0; mf < 4; ++mf)
        #pragma unroll
        for (int nf = 0; nf < 4; ++nf) {
            int n = n0 + wc * 64 + nf * 16 + (l & 15);
            #pragma unroll
            for (int r = 0; r < 4; ++r) {
                int m = m0 + wr * 64 + mf * 16 + (l >> 4) * 4 + r;
                Cz[(size_t)m * N + n] = acc[mf][nf][r];
            }
        }
}

// ---------------- split-K NT GEMM, atomic accumulate (g only) ----------------
__global__ __launch_bounds__(256) void mfma_nt_sk(
    const bf16* __restrict__ A, const bf16* __restrict__ Bt,
    float* __restrict__ C, int M, int N, int K, int KC)
{
    __shared__ __align__(16) bf16 As[128 * 32];
    __shared__ __align__(16) bf16 Bs[128 * 32];
    const int tid = threadIdx.x;
    const int w = tid >> 6, l = tid & 63;
    const int wr = w >> 1, wc = w & 1;
    const int m0 = blockIdx.y * 128, n0 = blockIdx.x * 128;
    const int kbeg = blockIdx.z * KC;

    f32x4v acc[4][4];
    #pragma unroll
    for (int a = 0; a < 4; ++a)
        #pragma unroll
        for (int b = 0; b < 4; ++b) acc[a][b] = (f32x4v){0.f, 0.f, 0.f, 0.f};

    const int srow = l >> 2;
    const int scol = (l & 3) * 8;

    for (int k0 = kbeg; k0 < kbeg + KC; k0 += 32) {
        #pragma unroll
        for (int q = 0; q < 2; ++q) {
            int r0 = w * 32 + q * 16;
            gload_lds16(&A[(size_t)(m0 + r0 + srow) * K + k0 + scol], &As[r0 * 32]);
            gload_lds16(&Bt[(size_t)(n0 + r0 + srow) * K + k0 + scol], &Bs[r0 * 32]);
        }
        __syncthreads();
        s16x8 af[4], bfr[4];
        #pragma unroll
        for (int mf = 0; mf < 4; ++mf)
            af[mf] = *(const s16x8*)&As[(wr * 64 + mf * 16 + (l & 15)) * 32 + (l >> 4) * 8];
        #pragma unroll
        for (int nf = 0; nf < 4; ++nf)
            bfr[nf] = *(const s16x8*)&Bs[(wc * 64 + nf * 16 + (l & 15)) * 32 + (l >> 4) * 8];
        #pragma unroll
        for (int mf = 0; mf < 4; ++mf)
            #pragma unroll
            for (int nf = 0; nf < 4; ++nf)
                acc[mf][nf] = __builtin_amdgcn_mfma_f32_16x16x32_bf16(af[mf], bfr[nf], acc[mf][nf], 0, 0, 0);
        __syncthreads();
    }

    #pragma unroll
    for (int mf = 0; mf < 4; ++mf)
        #pragma unroll
        for (int nf = 0; nf < 4; ++nf) {
            int n = n0 + wc * 64 + nf * 16 + (l & 15);
            #pragma unroll
            for (int r = 0; r < 4; ++r) {
                int m = m0 + wr * 64 + mf * 16 + (l >> 4) * 4 + r;
                atomicAdd(&C[(size_t)m * N + n], acc[mf][nf][r]);
            }
        }
}

// ---------------- e epilogue: sum NSL_ slabs, e = x - (v + b2), bf16 out ----------------
__global__ __launch_bounds__(256) void ep_ebf(const float* __restrict__ C8,
    const float* __restrict__ bias, const float* __restrict__ X,
    bf16* __restrict__ Eout, int MN, int N)
{
    const size_t SL = (size_t)MN;
    int base = (blockIdx.x * 256 + threadIdx.x) * 8;
    if (base < MN) {
        float v[8] = {0.f, 0.f, 0.f, 0.f, 0.f, 0.f, 0.f, 0.f};
        #pragma unroll
        for (int s = 0; s < NSL_; ++s) {
            float4 c0 = *(const float4*)&C8[s * SL + base];
            float4 c1 = *(const float4*)&C8[s * SL + base + 4];
            v[0] += c0.x; v[1] += c0.y; v[2] += c0.z; v[3] += c0.w;
            v[4] += c1.x; v[5] += c1.y; v[6] += c1.z; v[7] += c1.w;
        }
        float4 x0 = *(const float4*)&X[base];
        float4 x1 = *(const float4*)&X[base + 4];
        int n = base % N;
        float4 b0 = *(const float4*)&bias[n];
        float4 b1 = *(const float4*)&bias[n + 4];
        union { s16x8 vv; bf16 e[8]; } u;
        u.e[0] = __float2bfloat16(x0.x - (v[0] + b0.x));
        u.e[1] = __float2bfloat16(x0.y - (v[1] + b0.y));
        u.e[2] = __float2bfloat16(x0.z - (v[2] + b0.z));
        u.e[3] = __float2bfloat16(x0.w - (v[3] + b0.w));
        u.e[4] = __float2bfloat16(x1.x - (v[4] + b1.x));
        u.e[5] = __float2bfloat16(x1.y - (v[5] + b1.y));
        u.e[6] = __float2bfloat16(x1.z - (v[6] + b1.z));
        u.e[7] = __float2bfloat16(x1.w - (v[7] + b1.w));
        *(s16x8*)&Eout[base] = u.vv;
    }
}

// ---------------- recon epilogue + finalize ----------------
__global__ __launch_bounds__(256) void ep_recon_fin(const float* __restrict__ C8,
    const float* __restrict__ bias, const float* __restrict__ X,
    const float* __restrict__ sigma, const float* __restrict__ lsig, float* __restrict__ d_out)
{
    const size_t SL = (size_t)BS_ * D_;
    int m = blockIdx.x;
    float s = 0.f;
    for (int n = threadIdx.x * 4; n < D_; n += 1024) {
        size_t i = (size_t)m * D_ + n;
        float4 acc4 = (float4){0.f, 0.f, 0.f, 0.f};
        #pragma unroll
        for (int sl = 0; sl < NSL_; ++sl) {
            float4 c = *(const float4*)&C8[sl * SL + i];
            acc4.x += c.x; acc4.y += c.y; acc4.z += c.z; acc4.w += c.w;
        }
        float4 bb = *(const float4*)&bias[n];
        float4 xx = *(const float4*)&X[i];
        float v0 = acc4.x + bb.x - xx.x;
        float v1 = acc4.y + bb.y - xx.y;
        float v2 = acc4.z + bb.z - xx.z;
        float v3 = acc4.w + bb.w - xx.w;
        s += v0 * v0 + v1 * v1 + v2 * v2 + v3 * v3;
    }
    __shared__ float red[4];
    int wid = threadIdx.x >> 6, lane = threadIdx.x & 63;
    #pragma unroll
    for (int off = 32; off; off >>= 1) s += __shfl_xor(s, off);
    if (lane == 0) red[wid] = s;
    __syncthreads();
    if (threadIdx.x == 0) {
        float tot = red[0] + red[1] + red[2] + red[3];
        float sg = sigma[m];
        float rl = tot / (2.0f * sg * sg);
        float le = d_out[2 * 512 + m];
        float ld = d_out[3 * 512 + m];
        d_out[m] = (rl + le + ld) / 3072.0f + lsig[m];
        d_out[512 + m] = rl;
    }
}

// ---------------- fused J-GEMM + J^T J (counted-vmcnt 3-buffer + swizzle) ----------------
__global__ __launch_bounds__(256) void jtj_fused(
    const bf16* __restrict__ Vt, const bf16* __restrict__ W2t,
    float* __restrict__ S, int Mb, int b0)
{
    __shared__ union {
        struct { __align__(16) bf16 As[3][128 * 32]; __align__(16) bf16 Bs[3][128 * 32]; } s;
        __align__(16) bf16 J[128 * 136];
    } u;
    const int tid = threadIdx.x;
    const int w = tid >> 6, l = tid & 63;
    const int wr = w >> 1, wc = w & 1;

    int mb, nbk;
    if ((Mb & 7) == 0) {
        int lin = blockIdx.y * 24 + blockIdx.x;
        int xcd = lin & 7, idx = lin >> 3;
        int mchunk = Mb >> 3;
        mb = xcd * mchunk + idx / 24;
        nbk = idx % 24;
    } else { mb = blockIdx.y; nbk = blockIdx.x; }
    const int m0 = mb * 128, n0 = nbk * 128;

    f32x4v acc[4][4];
    #pragma unroll
    for (int a = 0; a < 4; ++a)
        #pragma unroll
        for (int b = 0; b < 4; ++b) acc[a][b] = (f32x4v){0.f, 0.f, 0.f, 0.f};

    const int strow = tid >> 2;
    const int scb = (((tid & 3) ^ ((tid >> 3) & 3)) << 4);

    auto STAGE = [&](int kt, int bi) {
        const char* a0 = (const char*)Vt  + ((size_t)(m0 + strow) * H_ + kt * 32) * 2 + scb;
        const char* b0p = (const char*)W2t + ((size_t)(n0 + strow) * H_ + kt * 32) * 2 + scb;
        char* la = (char*)u.s.As[bi] + w * 1024;
        char* lb = (char*)u.s.Bs[bi] + w * 1024;
        gload_lds16(a0, la);
        gload_lds16(a0 + (size_t)64 * H_ * 2, la + 4096);
        gload_lds16(b0p, lb);
        gload_lds16(b0p + (size_t)64 * H_ * 2, lb + 4096);
    };

    STAGE(0, 0);
    STAGE(1, 1);

    const int rdcb = (((l >> 4) ^ ((l >> 1) & 3)) << 4);

    for (int kt = 0; kt < H_ / 32; ++kt) {
        __builtin_amdgcn_sched_barrier(0);
        if (kt == H_ / 32 - 1) asm volatile("s_waitcnt vmcnt(0)" ::: "memory");
        else                   asm volatile("s_waitcnt vmcnt(4)" ::: "memory");
        __builtin_amdgcn_s_barrier();
        __builtin_amdgcn_sched_barrier(0);
        const int cur = kt % 3;
        const char* Ab = (const char*)u.s.As[cur];
        const char* Bb = (const char*)u.s.Bs[cur];
        s16x8 af[4], bfr[4];
        #pragma unroll
        for (int mf = 0; mf < 4; ++mf)
            af[mf] = *(const s16x8*)(Ab + (wr * 64 + mf * 16 + (l & 15)) * 64 + rdcb);
        #pragma unroll
        for (int nf = 0; nf < 4; ++nf)
            bfr[nf] = *(const s16x8*)(Bb + (wc * 64 + nf * 16 + (l & 15)) * 64 + rdcb);
        if (kt + 2 < H_ / 32) STAGE(kt + 2, (kt + 2) % 3);
        #pragma unroll
        for (int mf = 0; mf < 4; ++mf)
            #pragma unroll
            for (int nf = 0; nf < 4; ++nf)
                acc[mf][nf] = __builtin_amdgcn_mfma_f32_16x16x32_bf16(af[mf], bfr[nf], acc[mf][nf], 0, 0, 0);
    }

    __syncthreads();
    #pragma unroll
    for (int mf = 0; mf < 4; ++mf) {
        int rbase = wr * 64 + mf * 16 + (l >> 4) * 4;
        #pragma unroll
        for (int nf = 0; nf < 4; ++nf) {
            int col = wc * 64 + nf * 16 + (l & 15);
            #pragma unroll
            for (int r = 0; r < 4; ++r)
                u.J[(rbase + r) * 136 + col] = __float2bfloat16(acc[mf][nf][r]);
        }
    }
    __syncthreads();

    #pragma unroll
    for (int t2 = 0; t2 < 2; ++t2) {
        int bl = w * 2 + t2;
        f32x4v sp = (f32x4v){0.f, 0.f, 0.f, 0.f};
        #pragma unroll
        for (int kq = 0; kq < 4; ++kq) {
            s16x8 fr = *(const s16x8*)&u.J[(bl * 16 + (l & 15)) * 136 + kq * 32 + (l >> 4) * 8];
            sp = __builtin_amdgcn_mfma_f32_16x16x32_bf16(fr, fr, sp, 0, 0, 0);
        }
        int bglob = b0 + mb * 8 + bl;
        #pragma unroll
        for (int r = 0; r < 4; ++r)
            atomicAdd(&S[(size_t)bglob * 256 + ((l >> 4) * 4 + r) * 16 + (l & 15)], sp[r]);
    }
}

// ---------------- fused prep: casts + zero-fill in one launch ----------------
__global__ __launch_bounds__(256) void prep_all(
    const float* __restrict__ x, const float* __restrict__ enc_W1,
    const float* __restrict__ dec_W2, const float* __restrict__ dec_W1,
    bf16* __restrict__ x_bf, bf16* __restrict__ eW1t,
    bf16* __restrict__ W2t, bf16* __restrict__ W2b, bf16* __restrict__ W1b,
    float* __restrict__ zero_region)
{
    __shared__ float tile[64][65];
    const int blk = blockIdx.x;
    const int tid = threadIdx.x;
    if (blk < 768) {
        int i = blk * 256 + tid;
        const float4* p = (const float4*)x + (size_t)i * 2;
        float4 a = p[0], b = p[1];
        union { s16x8 v; bf16 e[8]; } u;
        u.e[0] = __float2bfloat16(a.x); u.e[1] = __float2bfloat16(a.y);
        u.e[2] = __float2bfloat16(a.z); u.e[3] = __float2bfloat16(a.w);
        u.e[4] = __float2bfloat16(b.x); u.e[5] = __float2bfloat16(b.y);
        u.e[6] = __float2bfloat16(b.z); u.e[7] = __float2bfloat16(b.w);
        *(s16x8*)&x_bf[(size_t)i * 8] = u.v;
    } else if (blk < 768 + 1536) {
        int bid = blk - 768;
        int r0 = (bid % 48) * 64, c0 = (bid / 48) * 64;
        int tx = tid & 63, ty = tid >> 6;
        #pragma unroll
        for (int k = 0; k < 16; ++k) {
            int rr = ty * 16 + k;
            tile[rr][tx] = enc_W1[(size_t)(r0 + rr) * H_ + c0 + tx];
        }
        __syncthreads();
        #pragma unroll
        for (int k = 0; k < 16; ++k) {
            int cc = ty * 16 + k;
            eW1t[(size_t)(c0 + cc) * D_ + r0 + tx] = __float2bfloat16(tile[tx][cc]);
        }
    } else if (blk < 768 + 3072) {
        int bid = blk - 768 - 1536;
        int r0 = (bid % 32) * 64, c0 = (bid / 32) * 64;
        int tx = tid & 63, ty = tid >> 6;
        #pragma unroll
        for (int k = 0; k < 16; ++k) {
            int rr = ty * 16 + k;
            float v = dec_W2[(size_t)(r0 + rr) * D_ + c0 + tx];
            tile[rr][tx] = v;
            W2b[(size_t)(r0 + rr) * D_ + c0 + tx] = __float2bfloat16(v);
        }
        __syncthreads();
        #pragma unroll
        for (int k = 0; k < 16; ++k) {
            int cc = ty * 16 + k;
            W2t[(size_t)(c0 + cc) * H_ + r0 + tx] = __float2bfloat16(tile[tx][cc]);
        }
    } else if (blk < 768 + 3072 + 16) {
        int i = (blk - 768 - 3072) * 256 + tid;
        if (i < N_ * H_ / 8) {
            const float4* p = (const float4*)dec_W1 + (size_t)i * 2;
            float4 a = p[0], b = p[1];
            union { s16x8 v; bf16 e[8]; } u;
            u.e[0] = __float2bfloat16(a.x); u.e[1] = __float2bfloat16(a.y);
            u.e[2] = __float2bfloat16(a.z); u.e[3] = __float2bfloat16(a.w);
            u.e[4] = __float2bfloat16(b.x); u.e[5] = __float2bfloat16(b.y);
            u.e[6] = __float2bfloat16(b.z); u.e[7] = __float2bfloat16(b.w);
            *(s16x8*)&W1b[(size_t)i * 8] = u.v;
        }
    } else {
        // zero-fill g + S (4.5 MB = 1152 blocks x 256 threads x 16 B)
        int i = (blk - 768 - 3072 - 16) * 256 + tid;
        *(float4*)&zero_region[(size_t)i * 4] = (float4){0.f, 0.f, 0.f, 0.f};
    }
}

// ---------------- zsig + build_t + build_vt fused ----------------
__global__ __launch_bounds__(256) void zsig_t_kernel(const float* __restrict__ Ch8,
    const float* __restrict__ enc_b1, const float* __restrict__ Wmu, const float* __restrict__ bmu,
    const float* __restrict__ Wls, const float* __restrict__ bls,
    const float* __restrict__ dW1, const float* __restrict__ db1,
    float* __restrict__ z_star, float* __restrict__ lsig, float* __restrict__ sigma,
    float* __restrict__ t, bf16* __restrict__ tb, bf16* __restrict__ Vt)
{
    const int b = blockIdx.x, tid = threadIdx.x;
    const size_t SL = (size_t)BS_ * H_;
    float acc[17];
    #pragma unroll
    for (int i = 0; i < 17; ++i) acc[i] = 0.f;
    for (int hh = tid; hh < H_; hh += 256) {
        size_t idx = (size_t)b * H_ + hh;
        float c = 0.f;
        #pragma unroll
        for (int s = 0; s < NSL_; ++s) c += Ch8[s * SL + idx];
        float hv = tanhf(c + enc_b1[hh]);
        const float* wr = &Wmu[(size_t)hh * 16];
        #pragma unroll
        for (int i = 0; i < 16; ++i) acc[i] += hv * wr[i];
        acc[16] += hv * Wls[hh];
    }
    __shared__ float red[17][4];
    __shared__ float zs[16];
    __shared__ float us[H_];
    const int wid = tid >> 6, lane = tid & 63;
    #pragma unroll
    for (int i = 0; i < 17; ++i) {
        float v = acc[i];
        #pragma unroll
        for (int off = 32; off; off >>= 1) v += __shfl_xor(v, off);
        if (lane == 0) red[i][wid] = v;
    }
    __syncthreads();
    if (tid < 17) {
        float v = red[tid][0] + red[tid][1] + red[tid][2] + red[tid][3];
        if (tid < 16) { float z = v + bmu[tid]; zs[tid] = z; z_star[(size_t)b * 16 + tid] = z; }
        else { float ls = v + bls[0]; lsig[b] = ls; sigma[b] = expf(ls); }
    }
    __syncthreads();
    for (int hh = tid; hh < H_; hh += 256) {
        float a = db1[hh];
        #pragma unroll
        for (int i = 0; i < 16; ++i) a += zs[i] * dW1[(size_t)i * H_ + hh];
        float tv = tanhf(a);
        t[(size_t)b * H_ + hh] = tv;
        tb[(size_t)b * H_ + hh] = __float2bfloat16(tv);
        us[hh] = 1.f - tv * tv;
    }
    if (Vt) {
        __syncthreads();
        size_t base = (size_t)b * 16 * H_;
        int hh = tid * 8;
        for (int i = 0; i < 16; ++i) {
            union { s16x8 v; bf16 e[8]; } pk;
            #pragma unroll
            for (int k = 0; k < 8; ++k)
                pk.e[k] = __float2bfloat16(us[hh + k] * dW1[(size_t)i * H_ + hh + k]);
            *(s16x8*)&Vt[base + (size_t)i * H_ + hh] = pk.v;
        }
    }
}

// t = tanh(z @ W1 + b1), bf16 out only
__global__ __launch_bounds__(256) void build_t(const float* __restrict__ z,
    const float* __restrict__ W1, const float* __restrict__ b1, bf16* __restrict__ tb)
{
    __shared__ float zs[16];
    int b = blockIdx.x, tid = threadIdx.x;
    if (tid < 16) zs[tid] = z[(size_t)b * 16 + tid];
    __syncthreads();
    for (int hh = tid; hh < H_; hh += 256) {
        float a = b1[hh];
        #pragma unroll
        for (int i = 0; i < 16; ++i) a += zs[i] * W1[(size_t)i * H_ + hh];
        tb[(size_t)b * H_ + hh] = __float2bfloat16(tanhf(a));
    }
}

// Vt chunk builder (fallback when workspace forces chunking)
__global__ __launch_bounds__(256) void build_vt(const float* __restrict__ t,
    const float* __restrict__ W1, bf16* __restrict__ Vt, int b0)
{
    int bl = blockIdx.x, b = b0 + bl, tid = threadIdx.x;
    __shared__ float u[H_];
    for (int hh = tid; hh < H_; hh += 256) {
        float tv = t[(size_t)b * H_ + hh];
        u[hh] = 1.f - tv * tv;
    }
    __syncthreads();
    size_t base = (size_t)bl * 16 * H_;
    int hh = tid * 8;
    for (int i = 0; i < 16; ++i) {
        union { s16x8 v; bf16 e[8]; } pk;
        #pragma unroll
        for (int k = 0; k < 8; ++k)
            pk.e[k] = __float2bfloat16(u[hh + k] * W1[(size_t)i * H_ + hh + k]);
        *(s16x8*)&Vt[base + (size_t)i * H_ + hh] = pk.v;
    }
}

// ---------------- fused hessian + solve: block = 4 batches ----------------
// Phase 1: wave w computes hessian core for batch blk*4+w into LDS.
// Phase 2: wave 0 solves all 4 batches (S_global + LDS hess).
__global__ __launch_bounds__(256) void solve_hess_kernel(
    const float* __restrict__ S, const float* __restrict__ t, const float* __restrict__ g,
    const bf16* __restrict__ W1b, const float* __restrict__ sigma,
    const float* __restrict__ z_star, const float* __restrict__ eps,
    float* __restrict__ z_sample, float* __restrict__ d_out)
{
    __shared__ float Sh[4][256];
    const int tid = threadIdx.x;
    {
        const int w = tid >> 6, l = tid & 63;
        const int b = blockIdx.x * 4 + w;
        const int row = l & 15, kq = (l >> 4) * 8;
        f32x4v sp = (f32x4v){0.f, 0.f, 0.f, 0.f};
        for (int k0 = 0; k0 < H_; k0 += 32) {
            int kk = k0 + kq;
            s16x8 wf = *(const s16x8*)&W1b[(size_t)row * H_ + kk];
            float4 t0 = *(const float4*)&t[(size_t)b * H_ + kk];
            float4 t1 = *(const float4*)&t[(size_t)b * H_ + kk + 4];
            float4 g0 = *(const float4*)&g[(size_t)b * H_ + kk];
            float4 g1 = *(const float4*)&g[(size_t)b * H_ + kk + 4];
            float wv[8];
            wv[0] = 2.f * g0.x * t0.x * (1.f - t0.x * t0.x);
            wv[1] = 2.f * g0.y * t0.y * (1.f - t0.y * t0.y);
            wv[2] = 2.f * g0.z * t0.z * (1.f - t0.z * t0.z);
            wv[3] = 2.f * g0.w * t0.w * (1.f - t0.w * t0.w);
            wv[4] = 2.f * g1.x * t1.x * (1.f - t1.x * t1.x);
            wv[5] = 2.f * g1.y * t1.y * (1.f - t1.y * t1.y);
            wv[6] = 2.f * g1.z * t1.z * (1.f - t1.z * t1.z);
            wv[7] = 2.f * g1.w * t1.w * (1.f - t1.w * t1.w);
            union { s16x8 v; bf16 e[8]; } af;
            #pragma unroll
            for (int e = 0; e < 8; ++e)
                af.e[e] = __float2bfloat16(wv[e] * bf2f((unsigned short)wf[e]));
            sp = __builtin_amdgcn_mfma_f32_16x16x32_bf16(af.v, wf, sp, 0, 0, 0);
        }
        #pragma unroll
        for (int r = 0; r < 4; ++r)
            Sh[w][((l >> 4) * 4 + r) * 16 + (l & 15)] = sp[r];
    }
    __syncthreads();
    if (tid >= 64) return;

    const int lane = tid;
    const int q = lane >> 4;
    const int j = lane & 15;
    const int b = blockIdx.x * 4 + q;

    const float sg = sigma[b];
    const float inv_s2 = 1.0f / (sg * sg);

    float a0[16], a[16];
    #pragma unroll
    for (int r = 0; r < 16; ++r) {
        a0[r] = (S[(size_t)b * 256 + r * 16 + j] + Sh[q][r * 16 + j]) * inv_s2 + ((r == j) ? 1.0f : 0.0f);
        a[r] = a0[r];
    }

    #pragma unroll
    for (int k = 0; k < 14; ++k) {
        float x[16];
        #pragma unroll
        for (int r = 0; r < 16; ++r) x[r] = __shfl(a[k], r, 16);
        float sig2 = 0.f;
        #pragma unroll
        for (int r = 0; r < 16; ++r) if (r > k + 1) sig2 += x[r] * x[r];
        float x0 = x[k + 1];
        float normx = sqrtf(sig2 + x0 * x0);
        float alpha = (x0 >= 0.f) ? -normx : normx;
        float v[16];
        #pragma unroll
        for (int r = 0; r < 16; ++r)
            v[r] = (r <= k) ? 0.f : ((r == k + 1) ? x0 - alpha : x[r]);
        float vtv = 0.f;
        #pragma unroll
        for (int r = 0; r < 16; ++r) vtv += v[r] * v[r];
        float beta = (vtv > 1e-28f) ? 2.0f / vtv : 0.f;
        float sj = 0.f;
        #pragma unroll
        for (int r = 0; r < 16; ++r) sj += a[r] * v[r];
        float av[16];
        #pragma unroll
        for (int r = 0; r < 16; ++r) av[r] = __shfl(sj, r, 16);
        float vtav = 0.f;
        #pragma unroll
        for (int r = 0; r < 16; ++r) vtav += v[r] * av[r];
        float c = 0.5f * beta * vtav;
        float wv[16];
        #pragma unroll
        for (int r = 0; r < 16; ++r) wv[r] = beta * (av[r] - c * v[r]);
        float vj = (j <= k) ? 0.f : ((j == k + 1) ? a[k] - alpha : a[k]);
        float wj = beta * (sj - c * vj);
        #pragma unroll
        for (int r = 0; r < 16; ++r) a[r] -= v[r] * wj + wv[r] * vj;
    }

    float dg[16], eo[15];
    #pragma unroll
    for (int r = 0; r < 16; ++r) dg[r] = __shfl(a[r], r, 16);
    #pragma unroll
    for (int r = 0; r < 15; ++r) eo[r] = __shfl(a[r + 1], r, 16);

    float lo = 1e30f, hi = 1e30f;
    #pragma unroll
    for (int r = 0; r < 16; ++r) {
        float rad = ((r > 0) ? fabsf(eo[r - 1]) : 0.f) + ((r < 15) ? fabsf(eo[r]) : 0.f);
        lo = fminf(lo, dg[r] - rad);
        hi = fminf(hi, dg[r]);
    }
    lo -= 1e-4f; hi += 1e-4f;

    #pragma unroll
    for (int pass = 0; pass < 5; ++pass) {
        float step = (hi - lo) * (1.0f / 17.0f);
        float s = lo + step * (float)(j + 1);
        float qq = dg[0] - s;
        int cnt = (qq < 0.f) ? 1 : 0;
        #pragma unroll
        for (int i = 1; i < 16; ++i) {
            float denom = (fabsf(qq) < 1e-30f) ? -1e-30f : qq;
            qq = dg[i] - s - eo[i - 1] * eo[i - 1] / denom;
            cnt += (qq < 0.f) ? 1 : 0;
        }
        unsigned long long bal = __ballot(cnt >= 1);
        unsigned grp = (unsigned)((bal >> (q * 16)) & 0xffffull);
        int f = grp ? (__ffs(grp) - 1) : 16;
        float nlo = lo + step * (float)f;
        float nhi = (f < 16) ? (lo + step * (float)(f + 1)) : hi;
        lo = nlo; hi = nhi;
    }
    const float lam_min = 0.5f * (lo + hi);
    const float delta = 10.0f - lam_min;

    float bm[16];
    #pragma unroll
    for (int r = 0; r < 16; ++r) bm[r] = a0[r] + ((r == j) ? delta : 0.f);

    float ldsum = 0.f;
    #pragma unroll
    for (int kk = 0; kk < 16; ++kk) {
        float ck[16];
        #pragma unroll
        for (int r = 0; r < 16; ++r) ck[r] = __shfl(bm[kk], r, 16);
        float dkk = sqrtf(fmaxf(ck[kk], 1e-30f));
        float inv = 1.0f / dkk;
        ldsum += logf(dkk);
        float lfull[16];
        #pragma unroll
        for (int r = 0; r < 16; ++r) lfull[r] = ck[r] * inv;
        float lj = bm[kk] * inv;
        if (j == kk) {
            #pragma unroll
            for (int r = 0; r < 16; ++r) bm[r] = (r >= kk) ? lfull[r] : 0.f;
        } else if (j > kk) {
            #pragma unroll
            for (int r = 0; r < 16; ++r)
                if (r > kk) bm[r] -= lfull[r] * lj;
        }
    }

    float w[16];
    #pragma unroll
    for (int r = 0; r < 16; ++r) w[r] = 0.f;
    #pragma unroll
    for (int i = 0; i < 16; ++i) {
        float row[16];
        #pragma unroll
        for (int kx = 0; kx < 16; ++kx) row[kx] = __shfl(bm[i], kx, 16);
        float sacc = 0.f;
        #pragma unroll
        for (int kx = 0; kx < 16; ++kx) if (kx < i) sacc += row[kx] * w[kx];
        float invd = 1.0f / row[i];
        float val = (i == j) ? invd : (-sacc * invd);
        w[i] = (i >= j) ? val : 0.f;
    }

    float tsum = 0.f;
    #pragma unroll
    for (int r = 0; r < 16; ++r) tsum += w[r] * w[r];
    float zv = z_star[(size_t)b * 16 + j];
    float ep = eps[(size_t)b * 16 + j];
    float epsv[16];
    #pragma unroll
    for (int r = 0; r < 16; ++r) epsv[r] = __shfl(ep, r, 16);
    float zoff = 0.f;
    #pragma unroll
    for (int r = 0; r < 16; ++r) zoff += w[r] * epsv[r];
    z_sample[(size_t)b * 16 + j] = zv + zoff;

    float zsq = zv * zv;
    #pragma unroll
    for (int off = 1; off < 16; off <<= 1) {
        tsum += __shfl_xor(tsum, off);
        zsq  += __shfl_xor(zsq, off);
    }
    if (j == 0) {
        d_out[2 * 512 + b] = 0.5f * zsq + 0.5f * tsum;
        d_out[3 * 512 + b] = ldsum;
        d_out[4 * 512 + b] = sg;
    }
}

extern "C" void kernel_launch(void* const* d_in, const int* in_sizes, int n_in,
                              void* d_out, int out_size, void* d_ws, size_t ws_size,
                              hipStream_t stream)
{
    const float* x       = (const float*)d_in[0];
    const float* eps     = (const float*)d_in[1];
    const float* enc_W1  = (const float*)d_in[2];
    const float* enc_b1  = (const float*)d_in[3];
    const float* enc_Wmu = (const float*)d_in[4];
    const float* enc_bmu = (const float*)d_in[5];
    const float* enc_Wls = (const float*)d_in[6];
    const float* enc_bls = (const float*)d_in[7];
    const float* dec_W1  = (const float*)d_in[8];
    const float* dec_b1  = (const float*)d_in[9];
    const float* dec_W2  = (const float*)d_in[10];
    const float* dec_b2  = (const float*)d_in[11];
    float* out = (float*)d_out;

    char* wsb = (char*)d_ws;
    size_t off = 0;
    auto alloc = [&](size_t bytes) -> void* {
        off = (off + 255) & ~(size_t)255;
        void* p = wsb + off;
        off += bytes;
        return p;
    };

    // contiguous zero region: g (4 MB) + S (0.5 MB) -> zeroed by prep_all
    float* g    = (float*)alloc((size_t)BS_ * H_ * 4);
    float* S    = (float*)alloc((size_t)BS_ * 256 * 4);

    float* Ch8  = (float*)alloc((size_t)NSL_ * BS_ * H_ * 4);   // 32 MB
    float* Cd8  = (float*)alloc((size_t)NSL_ * BS_ * D_ * 4);   // 48 MB
    float* t    = (float*)alloc((size_t)BS_ * H_ * 4);
    float* z_st = (float*)alloc((size_t)BS_ * 16 * 4);
    float* lsig = (float*)alloc(BS_ * 4);
    float* sigm = (float*)alloc(BS_ * 4);
    float* z_sm = (float*)alloc((size_t)BS_ * 16 * 4);
    bf16* x_bf  = (bf16*)alloc((size_t)BS_ * D_ * 2);
    bf16* eW1t  = (bf16*)alloc((size_t)H_ * D_ * 2);
    bf16* W2b   = (bf16*)alloc((size_t)H_ * D_ * 2);
    bf16* W2t   = (bf16*)alloc((size_t)D_ * H_ * 2);
    bf16* W1b   = (bf16*)alloc((size_t)N_ * H_ * 2);
    bf16* t_bf  = (bf16*)alloc((size_t)BS_ * H_ * 2);
    bf16* e_bf  = (bf16*)alloc((size_t)BS_ * D_ * 2);
    bf16* t2b   = (bf16*)alloc((size_t)BS_ * H_ * 2);

    int nb = 0;
    size_t base_off = off;
    const int cand[3] = {512, 128, 32};
    bf16* Vt = nullptr;
    for (int ci = 0; ci < 3; ++ci) {
        off = base_off;
        int n = cand[ci];
        bf16* vt = (bf16*)alloc((size_t)n * 16 * H_ * 2);
        if (off <= ws_size) { nb = n; Vt = vt; break; }
    }
    if (nb == 0) return;
    bf16* Vt_full = (nb == 512) ? Vt : nullptr;

    // prep: casts + zeroing (g+S) in one launch
    prep_all<<<dim3(768 + 3072 + 16 + 1152), 256, 0, stream>>>(
        x, enc_W1, dec_W2, dec_W1, x_bf, eW1t, W2t, W2b, W1b, g);

    // h partials (8 slabs) -> zsig (+t, +Vt when full)
    mfma_nt_slab<<<dim3(H_ / 128, BS_ / 128, NSL_), 256, 0, stream>>>(
        x_bf, eW1t, Ch8, BS_, H_, D_, D_ / NSL_);
    zsig_t_kernel<<<dim3(BS_), 256, 0, stream>>>(Ch8, enc_b1, enc_Wmu, enc_bmu, enc_Wls, enc_bls,
        dec_W1, dec_b1, z_st, lsig, sigm, t, t_bf, Vt_full);
    // e partials (8 slabs) -> e_bf
    mfma_nt_slab<<<dim3(D_ / 128, BS_ / 128, NSL_), 256, 0, stream>>>(
        t_bf, W2t, Cd8, BS_, D_, H_, H_ / NSL_);
    ep_ebf<<<dim3(BS_ * D_ / 8 / 256), 256, 0, stream>>>(Cd8, dec_b2, x, e_bf, BS_ * D_, D_);
    // g = e @ W2^T (atomic accumulate, z=4)
    mfma_nt_sk<<<dim3(H_ / 128, BS_ / 128, 4), 256, 0, stream>>>(
        e_bf, W2b, g, BS_, H_, D_, D_ / 4);

    // S = J^T J
    if (Vt_full) {
        jtj_fused<<<dim3(D_ / 128, 512 * 16 / 128), 256, 0, stream>>>(
            Vt_full, W2t, S, 512 * 16 / 128, 0);
    } else {
        for (int b0 = 0; b0 < BS_; b0 += nb) {
            build_vt<<<dim3(nb), 256, 0, stream>>>(t, dec_W1, Vt, b0);
            jtj_fused<<<dim3(D_ / 128, nb * 16 / 128), 256, 0, stream>>>(
                Vt, W2t, S, nb * 16 / 128, b0);
        }
    }

    // hess + eig-min / Cholesky / solves (fused)
    solve_hess_kernel<<<dim3(BS_ / 4), 256, 0, stream>>>(
        S, t, g, W1b, sigm, z_st, eps, z_sm, out);
    build_t<<<dim3(BS_), 256, 0, stream>>>(z_sm, dec_W1, dec_b1, t2b);
    // recon partials (8 slabs, reuse Cd8) -> fused rowsum + finalize
    mfma_nt_slab<<<dim3(D_ / 128, BS_ / 128, NSL_), 256, 0, stream>>>(
        t2b, W2t, Cd8, BS_, D_, H_, H_ / NSL_);
    ep_recon_fin<<<dim3(BS_), 256, 0, stream>>>(Cd8, dec_b2, x, sigm, lsig, out);
}